// Round 14
// baseline (356.313 us; speedup 1.0000x reference)
//
#include <hip/hip_runtime.h>
#include <hip/hip_bf16.h>

typedef __bf16 bf16;
typedef __bf16 bf16x8 __attribute__((ext_vector_type(8)));
typedef __bf16 bf16x4 __attribute__((ext_vector_type(4)));
typedef float  f32x4  __attribute__((ext_vector_type(4)));
typedef float  f32x16 __attribute__((ext_vector_type(16)));
typedef unsigned int u32x4 __attribute__((ext_vector_type(4)));

#define D_MODEL 2048
#define SEQ     2048
#define BATCH   2
#define NHEAD   16
#define HDIM    128
#define LATENT  256
#define BROWS   SEQ            // rows per batch = 2048

typedef __attribute__((address_space(1))) void gvoid;
typedef __attribute__((address_space(3))) void svoid;

__device__ __forceinline__ void gld16(const bf16* g, bf16* l) {
  // async global->LDS, 16B per lane; LDS dest must be lane-linear (it is).
  __builtin_amdgcn_global_load_lds((gvoid*)(void*)g, (svoid*)l, 16, 0, 0);
}

__device__ __forceinline__ f32x4 mfma16(bf16x8 a, bf16x8 b, f32x4 c) {
  return __builtin_amdgcn_mfma_f32_16x16x32_bf16(a, b, c, 0, 0, 0);
}
__device__ __forceinline__ f32x16 mfma32(bf16x8 a, bf16x8 b, f32x16 c) {
  return __builtin_amdgcn_mfma_f32_32x32x16_bf16(a, b, c, 0, 0, 0);
}

__device__ __forceinline__ unsigned cvt_pk_bf16(float lo, float hi) {
  unsigned r;
  asm("v_cvt_pk_bf16_f32 %0, %1, %2" : "=v"(r) : "v"(lo), "v"(hi));
  return r;
}

// Integer-bit NaN/Inf firewall (cannot be folded by fast-math).
__device__ __forceinline__ float fw(float v) {
  union { float f; unsigned u; } x; x.f = v;
  if ((x.u & 0x7f800000u) == 0x7f800000u) return 0.f;
  return v;
}

template<typename T>
__device__ __forceinline__ bf16x8 ld_cvt8(const T* p);
template<>
__device__ __forceinline__ bf16x8 ld_cvt8<float>(const float* p) {
  const float4 a = *(const float4*)p;
  const float4 b = *(const float4*)(p + 4);
  bf16x8 r;
  r[0] = (bf16)a.x; r[1] = (bf16)a.y; r[2] = (bf16)a.z; r[3] = (bf16)a.w;
  r[4] = (bf16)b.x; r[5] = (bf16)b.y; r[6] = (bf16)b.z; r[7] = (bf16)b.w;
  return r;
}
template<>
__device__ __forceinline__ bf16x8 ld_cvt8<bf16>(const bf16* p) {
  return *(const bf16x8*)p;
}

template<typename TC>
__device__ __forceinline__ void st_c(TC* p, float v);
template<> __device__ __forceinline__ void st_c<bf16>(bf16* p, float v)   { *p = (bf16)v; }
template<> __device__ __forceinline__ void st_c<float>(float* p, float v) { *p = v; }

// ---------------------------------------------------------------------------
// fp32 -> bf16 conversion, 8 elems/thread (float4 x2 -> bf16x8 store).
// ---------------------------------------------------------------------------
__global__ __launch_bounds__(256)
void cvt_bf16(const float* __restrict__ in, bf16* __restrict__ out, int n8)
{
  int i = blockIdx.x * 256 + threadIdx.x;
  if (i >= n8) return;
  const float4 a = ((const float4*)in)[2 * i];
  const float4 b = ((const float4*)in)[2 * i + 1];
  bf16x8 r;
  r[0] = (bf16)a.x; r[1] = (bf16)a.y; r[2] = (bf16)a.z; r[3] = (bf16)a.w;
  r[4] = (bf16)b.x; r[5] = (bf16)b.y; r[6] = (bf16)b.z; r[7] = (bf16)b.w;
  ((bf16x8*)out)[i] = r;
}

// Fused two-tensor conversion (one launch for x and wq).
__global__ __launch_bounds__(256)
void cvt2_bf16(const float* __restrict__ inA, bf16* __restrict__ outA, int n8A,
               const float* __restrict__ inB, bf16* __restrict__ outB, int n8B)
{
  int i = blockIdx.x * 256 + threadIdx.x;
  const float* in; bf16* out; int k;
  if (i < n8A) { in = inA; out = outA; k = i; }
  else {
    k = i - n8A;
    if (k >= n8B) return;
    in = inB; out = outB;
  }
  const float4 a = ((const float4*)in)[2 * k];
  const float4 b = ((const float4*)in)[2 * k + 1];
  bf16x8 r;
  r[0] = (bf16)a.x; r[1] = (bf16)a.y; r[2] = (bf16)a.z; r[3] = (bf16)a.w;
  r[4] = (bf16)b.x; r[5] = (bf16)b.y; r[6] = (bf16)b.z; r[7] = (bf16)b.w;
  ((bf16x8*)out)[k] = r;
}

// Fused wo-conversion + 16MB ctx copy (one launch; both memory-bound).
__global__ __launch_bounds__(256)
void cvt_copy(const float* __restrict__ wo, bf16* __restrict__ wob, int n8w,
              const bf16* __restrict__ src, bf16* __restrict__ dst, int n8c)
{
  int i = blockIdx.x * 256 + threadIdx.x;
  if (i < n8w) {
    const float4 a = ((const float4*)wo)[2 * i];
    const float4 b = ((const float4*)wo)[2 * i + 1];
    bf16x8 r;
    r[0] = (bf16)a.x; r[1] = (bf16)a.y; r[2] = (bf16)a.z; r[3] = (bf16)a.w;
    r[4] = (bf16)b.x; r[5] = (bf16)b.y; r[6] = (bf16)b.z; r[7] = (bf16)b.w;
    ((bf16x8*)wob)[i] = r;
  } else {
    int k = i - n8w;
    if (k >= n8c) return;
    ((bf16x8*)dst)[k] = ((const bf16x8*)src)[k];
  }
}

// ---------------------------------------------------------------------------
// Legacy reg-staged GEMM (kept for the per-batch fallback path).
// C[M][N] = A[M][K] @ W[N][K]^T (+ bias[col]). TRANSC=1 stores C^T (ld=M).
// ---------------------------------------------------------------------------
template<typename TA, typename TW, typename TC, int BIAS, int TRANSC>
__global__ __launch_bounds__(256)
void gemm_nt(const TA* __restrict__ A, const TW* __restrict__ W,
             TC* __restrict__ C, const float* __restrict__ bias,
             int M, int N, int K)
{
  const int t    = threadIdx.x;
  const int wave = t >> 6, lane = t & 63;
  const int quad = lane >> 4, l16 = lane & 15;
  const int wr = (wave >> 1) * 64, wc = (wave & 1) * 64;
  const int am0 = blockIdx.x * 128;
  const int bn0 = blockIdx.y * 128;

  __shared__ __align__(16) bf16 As[128][40];
  __shared__ __align__(16) bf16 Bs[128][40];

  const f32x4 fzero = {0.f, 0.f, 0.f, 0.f};
  f32x4 acc[4][4];
#pragma unroll
  for (int i = 0; i < 4; i++)
#pragma unroll
    for (int j = 0; j < 4; j++) acc[i][j] = fzero;

  const int srow = t >> 2;
  const int scol = (t & 3) * 8;

  for (int k0 = 0; k0 < K; k0 += 32) {
#pragma unroll
    for (int c = 0; c < 2; c++) {
      int row = srow + c * 64;
      *(bf16x8*)(&As[row][scol]) =
        ld_cvt8<TA>(A + (size_t)(am0 + row) * K + k0 + scol);
      *(bf16x8*)(&Bs[row][scol]) =
        ld_cvt8<TW>(W + (size_t)(bn0 + row) * K + k0 + scol);
    }
    __syncthreads();

    bf16x8 af[4], bfr[4];
#pragma unroll
    for (int i = 0; i < 4; i++)
      af[i]  = *(const bf16x8*)(&As[wr + i*16 + l16][quad*8]);
#pragma unroll
    for (int j = 0; j < 4; j++)
      bfr[j] = *(const bf16x8*)(&Bs[wc + j*16 + l16][quad*8]);
#pragma unroll
    for (int i = 0; i < 4; i++)
#pragma unroll
      for (int j = 0; j < 4; j++)
        acc[i][j] = mfma16(af[i], bfr[j], acc[i][j]);
    __syncthreads();
  }

#pragma unroll
  for (int i = 0; i < 4; i++) {
#pragma unroll
    for (int j = 0; j < 4; j++) {
      int col = bn0 + wc + j*16 + l16;
      float bv = 0.f;
      if (BIAS) bv = bias[col];
#pragma unroll
      for (int r = 0; r < 4; r++) {
        int row = am0 + wr + i*16 + quad*4 + r;   // C/D: col=lane&15, row=quad*4+reg
        if (TRANSC)
          st_c<TC>(&C[(size_t)col * M + row], fw(acc[i][j][r] + bv));
        else
          st_c<TC>(&C[(size_t)row * N + col], fw(acc[i][j][r] + bv));
      }
    }
  }
}

// ---------------------------------------------------------------------------
// m97-structure GEMM, 8-WAVE, BK=64: A,W bf16 via global_load_lds into LINEAR
// LDS. 128x128 tile, 512 threads / 8 waves (each wave 64x32 = 4x2 MFMA).
// BK=64 halves barrier count vs BK=32: per iteration, stage 2 chunks/thread/
// operand -> 1 barrier -> kk-loop{6 frag loads, 8 MFMA}x2 -> 1 barrier.
// MFMA/barrier-pair back to 16 (the m97 amortization point). Frags loaded
// per-kk so live-register count is unchanged (no r11-style spill).
// LDS 32 KB/block, 2 blocks/CU = 64 KB. r10 measured 8-wave: total -17us.
// ---------------------------------------------------------------------------
template<typename TC, int BIAS, int TRANSC>
__global__ __launch_bounds__(512, 4)
void gemm_bb(const bf16* __restrict__ A, const bf16* __restrict__ W,
             TC* __restrict__ C, const float* __restrict__ bias,
             int M, int N, int K)
{
  const int t    = threadIdx.x;
  const int wave = t >> 6, lane = t & 63;
  const int quad = lane >> 4, l16 = lane & 15;
  const int wr = (wave >> 2) * 64, wc = (wave & 3) * 32;
  const int am0 = blockIdx.x * 128;
  const int bn0 = blockIdx.y * 128;

  __shared__ __align__(16) bf16 As[128 * 64];   // 16 KB
  __shared__ __align__(16) bf16 Bs[128 * 64];   // 16 KB

  const f32x4 fzero = {0.f, 0.f, 0.f, 0.f};
  f32x4 acc[4][2];
#pragma unroll
  for (int i = 0; i < 4; i++)
#pragma unroll
    for (int j = 0; j < 2; j++) acc[i][j] = fzero;

  const int srow = t >> 3;          // 0..63
  const int scol = (t & 7) * 8;     // 0..56

  for (int k0 = 0; k0 < K; k0 += 64) {
    gld16(A + (size_t)(am0 + srow)      * K + k0 + scol, As + t * 8);
    gld16(A + (size_t)(am0 + 64 + srow) * K + k0 + scol, As + (t + 512) * 8);
    gld16(W + (size_t)(bn0 + srow)      * K + k0 + scol, Bs + t * 8);
    gld16(W + (size_t)(bn0 + 64 + srow) * K + k0 + scol, Bs + (t + 512) * 8);
    __syncthreads();                  // compiler drains vmcnt before barrier

#pragma unroll
    for (int kk = 0; kk < 2; kk++) {
      bf16x8 af[4], bfr[2];
#pragma unroll
      for (int i = 0; i < 4; i++)
        af[i]  = *(const bf16x8*)(As + (size_t)(wr + i*16 + l16) * 64 + kk*32 + quad * 8);
#pragma unroll
      for (int j = 0; j < 2; j++)
        bfr[j] = *(const bf16x8*)(Bs + (size_t)(wc + j*16 + l16) * 64 + kk*32 + quad * 8);
#pragma unroll
      for (int i = 0; i < 4; i++)
#pragma unroll
        for (int j = 0; j < 2; j++)
          acc[i][j] = mfma16(af[i], bfr[j], acc[i][j]);
    }
    __syncthreads();
  }

#pragma unroll
  for (int i = 0; i < 4; i++) {
#pragma unroll
    for (int j = 0; j < 2; j++) {
      int col = bn0 + wc + j*16 + l16;
      float bv = 0.f;
      if (BIAS) bv = bias[col];
#pragma unroll
      for (int r = 0; r < 4; r++) {
        int row = am0 + wr + i*16 + quad*4 + r;
        if (TRANSC)
          st_c<TC>(&C[(size_t)col * M + row], fw(acc[i][j][r] + bv));
        else
          st_c<TC>(&C[(size_t)row * N + col], fw(acc[i][j][r] + bv));
      }
    }
  }
}

// ---------------------------------------------------------------------------
// Fused K+V up-projection, 8-WAVE, BK=64: grid (M/128, N/128, 2). z=0 ->
// K = Lt @ wuk^T (row-major Ck); z=1 -> V^T (Cv, ld=M). A bf16 via
// global_load_lds (linear); W fp32 reg-staged+cvt (padded LDS).
// 1024 blocks = 4 blocks/CU; halves the launch tail vs two launches.
// ---------------------------------------------------------------------------
__global__ __launch_bounds__(512, 4)
void gemm_kv(const bf16* __restrict__ A,
             const float* __restrict__ Wk, const float* __restrict__ Wv,
             bf16* __restrict__ Ck, bf16* __restrict__ Cv,
             int M, int N, int K)
{
  const int z    = blockIdx.z;
  const float* W = z ? Wv : Wk;
  const int t    = threadIdx.x;
  const int wave = t >> 6, lane = t & 63;
  const int quad = lane >> 4, l16 = lane & 15;
  const int wr = (wave >> 2) * 64, wc = (wave & 3) * 32;
  const int am0 = blockIdx.x * 128;
  const int bn0 = blockIdx.y * 128;

  __shared__ __align__(16) bf16 As[128 * 64];   // 16 KB
  __shared__ __align__(16) bf16 Bs[128][72];    // 18 KB (64+8 pad)

  const f32x4 fzero = {0.f, 0.f, 0.f, 0.f};
  f32x4 acc[4][2];
#pragma unroll
  for (int i = 0; i < 4; i++)
#pragma unroll
    for (int j = 0; j < 2; j++) acc[i][j] = fzero;

  const int srow = t >> 3;          // 0..63
  const int scol = (t & 7) * 8;     // 0..56

  for (int k0 = 0; k0 < K; k0 += 64) {
    gld16(A + (size_t)(am0 + srow)      * K + k0 + scol, As + t * 8);
    gld16(A + (size_t)(am0 + 64 + srow) * K + k0 + scol, As + (t + 512) * 8);
    *(bf16x8*)(&Bs[srow][scol]) =
      ld_cvt8<float>(W + (size_t)(bn0 + srow) * K + k0 + scol);
    *(bf16x8*)(&Bs[64 + srow][scol]) =
      ld_cvt8<float>(W + (size_t)(bn0 + 64 + srow) * K + k0 + scol);
    __syncthreads();

#pragma unroll
    for (int kk = 0; kk < 2; kk++) {
      bf16x8 af[4], bfr[2];
#pragma unroll
      for (int i = 0; i < 4; i++)
        af[i]  = *(const bf16x8*)(As + (size_t)(wr + i*16 + l16) * 64 + kk*32 + quad * 8);
#pragma unroll
      for (int j = 0; j < 2; j++)
        bfr[j] = *(const bf16x8*)(&Bs[wc + j*16 + l16][kk*32 + quad*8]);
#pragma unroll
      for (int i = 0; i < 4; i++)
#pragma unroll
        for (int j = 0; j < 2; j++)
          acc[i][j] = mfma16(af[i], bfr[j], acc[i][j]);
    }
    __syncthreads();
  }

#pragma unroll
  for (int i = 0; i < 4; i++) {
#pragma unroll
    for (int j = 0; j < 2; j++) {
      int col  = bn0 + wc + j*16 + l16;
      int row0 = am0 + wr + i*16 + quad*4;
      if (z) {                         // V^T: 4 consecutive rows -> bf16x4
        bf16x4 o4;
#pragma unroll
        for (int r = 0; r < 4; r++) o4[r] = (bf16)fw(acc[i][j][r]);
        *(bf16x4*)(Cv + (size_t)col * M + row0) = o4;
      } else {                         // K: row-major scalar stores
#pragma unroll
        for (int r = 0; r < 4; r++)
          Ck[(size_t)(row0 + r) * N + col] = (bf16)fw(acc[i][j][r]);
      }
    }
  }
}

// ---------------------------------------------------------------------------
// Split-K GEMM, 8-WAVE, BK=64, for the latent projection (M=4096, N=256,
// K=2048): grid (M/128, N/128, SPLITK). Each z-slice computes a K-chunk
// partial into Cp[z][M][N] (f32). Deterministic; reduce_sk sums.
// ---------------------------------------------------------------------------
template<int SPLITK>
__global__ __launch_bounds__(512, 4)
void gemm_bf_sk(const bf16* __restrict__ A, const float* __restrict__ W,
                float* __restrict__ Cp, int M, int N, int K)
{
  const int t    = threadIdx.x;
  const int wave = t >> 6, lane = t & 63;
  const int quad = lane >> 4, l16 = lane & 15;
  const int wr = (wave >> 2) * 64, wc = (wave & 3) * 32;
  const int am0 = blockIdx.x * 128;
  const int bn0 = blockIdx.y * 128;
  const int kbeg = blockIdx.z * (K / SPLITK);
  const int kend = kbeg + K / SPLITK;

  __shared__ __align__(16) bf16 As[128 * 64];
  __shared__ __align__(16) bf16 Bs[128][72];

  const f32x4 fzero = {0.f, 0.f, 0.f, 0.f};
  f32x4 acc[4][2];
#pragma unroll
  for (int i = 0; i < 4; i++)
#pragma unroll
    for (int j = 0; j < 2; j++) acc[i][j] = fzero;

  const int srow = t >> 3;
  const int scol = (t & 7) * 8;

  for (int k0 = kbeg; k0 < kend; k0 += 64) {
    gld16(A + (size_t)(am0 + srow)      * K + k0 + scol, As + t * 8);
    gld16(A + (size_t)(am0 + 64 + srow) * K + k0 + scol, As + (t + 512) * 8);
    *(bf16x8*)(&Bs[srow][scol]) =
      ld_cvt8<float>(W + (size_t)(bn0 + srow) * K + k0 + scol);
    *(bf16x8*)(&Bs[64 + srow][scol]) =
      ld_cvt8<float>(W + (size_t)(bn0 + 64 + srow) * K + k0 + scol);
    __syncthreads();

#pragma unroll
    for (int kk = 0; kk < 2; kk++) {
      bf16x8 af[4], bfr[2];
#pragma unroll
      for (int i = 0; i < 4; i++)
        af[i]  = *(const bf16x8*)(As + (size_t)(wr + i*16 + l16) * 64 + kk*32 + quad * 8);
#pragma unroll
      for (int j = 0; j < 2; j++)
        bfr[j] = *(const bf16x8*)(&Bs[wc + j*16 + l16][kk*32 + quad*8]);
#pragma unroll
      for (int i = 0; i < 4; i++)
#pragma unroll
        for (int j = 0; j < 2; j++)
          acc[i][j] = mfma16(af[i], bfr[j], acc[i][j]);
    }
    __syncthreads();
  }

  float* Cb = Cp + (size_t)blockIdx.z * M * N;
#pragma unroll
  for (int i = 0; i < 4; i++)
#pragma unroll
    for (int j = 0; j < 2; j++) {
      int col = bn0 + wc + j*16 + l16;
#pragma unroll
      for (int r = 0; r < 4; r++) {
        int row = am0 + wr + i*16 + quad*4 + r;
        Cb[(size_t)row * N + col] = acc[i][j][r];
      }
    }
}

// Sum SPLITK f32 partials -> bf16 out. 4 outputs/thread (float4 loads).
template<int SPLITK>
__global__ __launch_bounds__(256)
void reduce_sk(const float* __restrict__ Cp, bf16* __restrict__ out, int MN)
{
  int i4 = (blockIdx.x * 256 + threadIdx.x) * 4;
  if (i4 >= MN) return;
  float4 s = *(const float4*)(Cp + i4);
#pragma unroll
  for (int k = 1; k < SPLITK; k++) {
    float4 p = *(const float4*)(Cp + (size_t)k * MN + i4);
    s.x += p.x; s.y += p.y; s.z += p.z; s.w += p.w;
  }
  bf16x4 o;
  o[0] = (bf16)fw(s.x); o[1] = (bf16)fw(s.y);
  o[2] = (bf16)fw(s.z); o[3] = (bf16)fw(s.w);
  *(bf16x4*)(out + i4) = o;
}

// ---------------------------------------------------------------------------
// RoPE in place on Q and K, layout [Mtot][2048]; seq pos = row & 2047.
// Vectorized: thread handles 8 consecutive j (bf16x8 loads/stores, 16B).
// Threads = Mtot * 16 heads * 8 jgroups.
// ---------------------------------------------------------------------------
__global__ __launch_bounds__(256)
void rope_kernel(bf16* __restrict__ Q, bf16* __restrict__ Kr)
{
  int idx = blockIdx.x * 256 + threadIdx.x;
  int jg  = idx & 7;
  int h   = (idx >> 3) & 15;
  int row = idx >> 7;
  int s   = row & (SEQ - 1);

  size_t base = (size_t)row * D_MODEL + h * HDIM + jg * 8;
  bf16x8 q1 = *(const bf16x8*)(Q  + base);
  bf16x8 q2 = *(const bf16x8*)(Q  + base + 64);
  bf16x8 k1 = *(const bf16x8*)(Kr + base);
  bf16x8 k2 = *(const bf16x8*)(Kr + base + 64);
  bf16x8 q1o, q2o, k1o, k2o;
#pragma unroll
  for (int u = 0; u < 8; u++) {
    int j = jg * 8 + u;
    float invf = exp2f(-0.2076205059304601f * (float)j);  // 10000^(-j/64)
    float ang  = (float)s * invf;
    float c, si;
    sincosf(ang, &si, &c);
    float a1 = (float)q1[u], a2 = (float)q2[u];
    q1o[u] = (bf16)(a1 * c - a2 * si);
    q2o[u] = (bf16)(a2 * c + a1 * si);
    float b1 = (float)k1[u], b2 = (float)k2[u];
    k1o[u] = (bf16)(b1 * c - b2 * si);
    k2o[u] = (bf16)(b2 * c + b1 * si);
  }
  *(bf16x8*)(Q  + base)      = q1o;
  *(bf16x8*)(Q  + base + 64) = q2o;
  *(bf16x8*)(Kr + base)      = k1o;
  *(bf16x8*)(Kr + base + 64) = k2o;
}

// ---------------------------------------------------------------------------
// Causal flash attention v2 (best measured: 76.2-81.6us; KVBLK=64).
// CLOSED factor matrix r3-r12: setprio -7us; XCD decode + ls[4] -6us;
// 8-wave merge -10us; dbuf -4us; KVBLK=128 -36us (VGPR spill). KVBLK=64
// is exactly the tile size whose full K/V prefetch fits in registers.
// Swapped-operand 32x32x16 MFMA + fully in-register softmax (T12).
// Block = (128 q-rows, head, batch); 4 waves x 32 q-rows; KV tile 64,
// single-buffer LDS, commit -> sync -> prefetch-issue -> compute -> sync.
// Complementary-qt pairing: blocks L and L+256 get qt=a / 15-a.
// O may alias Q (block-local region).
// ---------------------------------------------------------------------------
__global__ __launch_bounds__(256, 2)
void flash_attn(const bf16* __restrict__ Q, const bf16* __restrict__ Kc,
                const bf16* __restrict__ VT, bf16* __restrict__ O, int ldVT)
{
  const int L    = blockIdx.x;
  const int half = L >> 8;            // 0 or 1 (full path); 0 (per-batch)
  const int Mn   = L & 255;
  const int h    = Mn >> 4;
  const int a    = Mn & 15;
  const int qt   = half ? 15 - a : a; // complementary pairing
  const int b    = half;
  const int t    = threadIdx.x;
  const int wave = t >> 6, lane = t & 63;
  const int m31  = lane & 31, hi = lane >> 5;
  const int rowbase = b * SEQ;

  __shared__ __align__(16) bf16 Ks[64 * 128];   // 16 KB, rows 256B, XOR-swz
  __shared__ __align__(16) bf16 Vs[128 * 64];   // 16 KB, V^T rows 128B, XOR-swz

  // Q fragments (B-operand): lane holds Q[q=m31][d = dk*16 + hi*8 + j]
  bf16x8 qf[8];
  {
    const bf16* qp = Q + (size_t)(rowbase + qt*128 + wave*32 + m31) * D_MODEL
                   + h * HDIM + hi * 8;
#pragma unroll
    for (int dk = 0; dk < 8; dk++)
      qf[dk] = *(const bf16x8*)(qp + dk * 16);
  }

  f32x16 oacc[4];                     // C[m=d][n=q]: d = db*32 + crow(r,hi)
#pragma unroll
  for (int db = 0; db < 4; db++)
#pragma unroll
    for (int i = 0; i < 16; i++) oacc[db][i] = 0.f;
  float lsum = 0.f;

  // scale folded into exp2 domain: log2(e)/sqrt(128)
  const float SC2 = 0.12752051581562927f;

  const int ktmax = 2*qt + 1;
  const bf16* kbase0 = Kc + (size_t)rowbase * D_MODEL + h * HDIM;
  const bf16* vbase0 = VT + (size_t)(h*HDIM) * ldVT + rowbase;

  bf16x8 kr[4], vr[4];
#pragma unroll
  for (int c = 0; c < 4; c++) {          // prefetch tile 0
    int e = c*256 + t;
    kr[c] = *(const bf16x8*)(kbase0 + (size_t)(e >> 4) * D_MODEL + (e & 15) * 8);
    vr[c] = *(const bf16x8*)(vbase0 + (size_t)(e >> 3) * ldVT + (e & 7) * 8);
  }

  for (int kt = 0; kt <= ktmax; kt++) {
    // ---- commit prefetched tile to LDS (XOR-swizzled chunks) ----
#pragma unroll
    for (int c = 0; c < 4; c++) {
      int e = c*256 + t;
      int krow = e >> 4, kch = e & 15;
      *(bf16x8*)(Ks + krow * 128 + ((kch ^ (krow & 7)) * 8)) = kr[c];
      int vrow = e >> 3, vch = e & 7;
      *(bf16x8*)(Vs + vrow * 64  + ((vch ^ (vrow & 7)) * 8)) = vr[c];
    }
    __syncthreads();

    // ---- prefetch next tile into regs (overlaps compute below) ----
    if (kt < ktmax) {
      const bf16* kb = kbase0 + (size_t)((kt+1)*64) * D_MODEL;
      const bf16* vb = vbase0 + (kt+1)*64;
#pragma unroll
      for (int c = 0; c < 4; c++) {
        int e = c*256 + t;
        kr[c] = *(const bf16x8*)(kb + (size_t)(e >> 4) * D_MODEL + (e & 15) * 8);
        vr[c] = *(const bf16x8*)(vb + (size_t)(e >> 3) * ldVT + (e & 7) * 8);
      }
    }

    const int kvoff = kt*64 - qt*128;    // >=0 only for the 2 diagonal tiles
    // wave fully masked for this tile? (kvoff==64 and q_local <= 63)
    const bool activ = (kvoff < 0) | (kvoff <= wave*32 + 31);

    if (activ) {
      unsigned pb[4][4];                 // [kc 16-k chunk][B-frag dword]
#pragma unroll
      for (int kb = 0; kb < 2; kb++) {
        // ---- S^T = K Q^T (32k x 32q) ----
        f32x16 s;
#pragma unroll
        for (int i = 0; i < 16; i++) s[i] = 0.f;
        const int krow = kb*32 + m31;
        const bf16* ksrow = Ks + krow * 128;
        const int swz = (krow & 7);
#pragma unroll
        for (int dk = 0; dk < 8; dk++) {
          bf16x8 kf = *(const bf16x8*)(ksrow + (((dk*2 + hi) ^ swz) * 8));
          s = mfma32(kf, qf[dk], s);
        }

        // ---- static-max softmax numerator, lane-local ----
        float p[16];
        const int kq = kvoff + kb*32 + 4*hi - (wave*32 + m31);  // k - q offset
#pragma unroll
        for (int r = 0; r < 16; r++) {
          float v = s[r] * SC2;
          const int kk = (r & 3) + 8 * (r >> 2);
          if (kvoff >= 0 && (kq + kk) > 0) v = -1e30f;
          float e2 = exp2f(v);
          lsum += e2;
          p[r] = e2;
        }

        // ---- pack to PV B-operand: cvt_pk pairs + permlane32 half-swap ----
#pragma unroll
        for (int c = 0; c < 2; c++) {
          unsigned a0 = cvt_pk_bf16(p[(2*c)*4 + 0],   p[(2*c)*4 + 1]);
          unsigned a1 = cvt_pk_bf16(p[(2*c)*4 + 2],   p[(2*c)*4 + 3]);
          unsigned b0 = cvt_pk_bf16(p[(2*c+1)*4 + 0], p[(2*c+1)*4 + 1]);
          unsigned b1 = cvt_pk_bf16(p[(2*c+1)*4 + 2], p[(2*c+1)*4 + 3]);
          asm("v_permlane32_swap_b32 %0, %1" : "+v"(a0), "+v"(b0));
          asm("v_permlane32_swap_b32 %0, %1" : "+v"(a1), "+v"(b1));
          pb[kb*2 + c][0] = a0; pb[kb*2 + c][1] = a1;
          pb[kb*2 + c][2] = b0; pb[kb*2 + c][3] = b1;
        }
      }

      // ---- O^T += V^T P^T : C[m=d][n=q], A = V^T frags from LDS ----
#pragma unroll
      for (int db = 0; db < 4; db++) {
        const int vrow = db*32 + m31;
        const bf16* vsrow = Vs + vrow * 64;
        const int swz = (vrow & 7);
#pragma unroll
        for (int kc = 0; kc < 4; kc++) {
          bf16x8 vf = *(const bf16x8*)(vsrow + (((kc*2 + hi) ^ swz) * 8));
          u32x4 w = {pb[kc][0], pb[kc][1], pb[kc][2], pb[kc][3]};
          oacc[db] = mfma32(vf, __builtin_bit_cast(bf16x8, w), oacc[db]);
        }
      }
    }
    __syncthreads();
  }

  // ---- epilogue: combine half-row sums, scale, store (8B packed) ----
  const float ltot = lsum + __shfl_xor(lsum, 32, 64);
  const float invl = 1.f / ltot;
  const size_t ob = (size_t)(rowbase + qt*128 + wave*32 + m31) * D_MODEL + h * HDIM;
#pragma unroll
  for (int db = 0; db < 4; db++) {
#pragma unroll
    for (int q2 = 0; q2 < 4; q2++) {
      bf16x4 o4;
#pragma unroll
      for (int rr = 0; rr < 4; rr++)
        o4[rr] = (bf16)(oacc[db][q2*4 + rr] * invl);   // d = db*32+q2*8+hi*4+rr
      *(bf16x4*)(O + ob + db*32 + q2*8 + hi*4) = o4;
    }
  }
}

// ---------------------------------------------------------------------------
// Inputs FP32, output FP32. Path chosen by ws_size (deterministic, graph-safe).
//
// Full-path ws layout (35.65 MB == NEED_FULL, aliasing by liveness):
//   [0,16MB)  Kb   (K bf16)   <- holds wqb (8MB) until Q-GEMM, then split-K
//                                partials [0,32MB) until reduce_sk
//   [16,32MB) VTb  (V^T bf16) <- partials overlap; later wob (8MB) after attn
//   [32,34MB) Lt   (latent bf16)
// d_out scratch: [0,16MB) Q/ctx bf16; [16,32MB) xb (x in bf16, dead before
// the final fp32 output write).
// ---------------------------------------------------------------------------
extern "C" void kernel_launch(void* const* d_in, const int* in_sizes, int n_in,
                              void* d_out, int out_size, void* d_ws, size_t ws_size,
                              hipStream_t stream)
{
  const float* x    = (const float*)d_in[0];
  const float* wq   = (const float*)d_in[1];
  const float* wdkv = (const float*)d_in[2];
  const float* wuk  = (const float*)d_in[3];
  const float* wuv  = (const float*)d_in[4];
  const float* wo   = (const float*)d_in[5];
  const float* bo   = (const float*)d_in[6];
  float* out = (float*)d_out;

  const size_t MTOT = (size_t)BATCH * BROWS;              // 4096
  const size_t NEED_FULL = (MTOT * D_MODEL + (size_t)D_MODEL * MTOT
                          + MTOT * LATENT) * sizeof(bf16);  // 35.7 MB

  if (ws_size >= NEED_FULL) {
    // ---------------- FULL-BATCH PATH ----------------
    bf16* Kb  = (bf16*)d_ws;                         // [4096][2048]
    bf16* VTb = Kb  + MTOT * D_MODEL;                // [2048][4096]
    bf16* Lt  = VTb + (size_t)D_MODEL * MTOT;        // [4096][256]
    bf16* wqb = Kb;                                  // aliases Kb (8 MB)
    bf16* wob = VTb;                                 // aliases VTb (8 MB)
    float* Pp = (float*)d_ws;                        // split-K partials, 32 MB
    bf16* sb  = (bf16*)out;                          // Q/ctx bf16, d_out[0,16M)
    bf16* xb  = sb + MTOT * D_MODEL;                 // x bf16,    d_out[16,32M)

    const int n8x = (int)(MTOT * D_MODEL / 8);                 // 1048576
    const int n8w = (int)((size_t)D_MODEL * D_MODEL / 8);      // 524288

    // 1) conversions: x (16MB bf16) and wq (8MB bf16), one fused launch
    cvt2_bf16<<<(n8x + n8w) / 256, 256, 0, stream>>>(x, xb, n8x, wq, wqb, n8w);

    // 2) Q = xb @ wqb^T  (8-wave BK=64 GEMM) -- must precede partial writes
    gemm_bb<bf16, 0, 0><<<dim3(32, 16), 512, 0, stream>>>(xb, wqb, sb, nullptr, (int)MTOT, D_MODEL, D_MODEL);

    // 3) latent: Lt = xb @ wdkv^T via split-K 8 (partials in dead Kb+VTb)
    gemm_bf_sk<8><<<dim3(32, 2, 8), 512, 0, stream>>>(xb, wdkv, Pp, (int)MTOT, LATENT, D_MODEL);
    reduce_sk<8><<<(int)(MTOT * LATENT / 4 / 256), 256, 0, stream>>>(Pp, Lt, (int)(MTOT * LATENT));
    //    xb, wqb, partials dead from here
    // 4) K and V^T in ONE launch (1024 blocks = 4 blocks/CU)
    gemm_kv<<<dim3(32, 16, 2), 512, 0, stream>>>(Lt, wuk, wuv, Kb, VTb, (int)MTOT, D_MODEL, LATENT);

    rope_kernel<<<(int)(MTOT * NHEAD * 8) / 256, 256, 0, stream>>>(sb, Kb);

    flash_attn<<<dim3(512), 256, 0, stream>>>(sb, Kb, VTb, sb, (int)MTOT);

    // 5) wo -> bf16 into dead VTb region + ctx -> dead Kb region, one launch
    cvt_copy<<<(n8w + n8x) / 256 + 1, 256, 0, stream>>>(wo, wob, n8w, sb, Kb, n8x);

    // 6) out = ctx @ wob^T + bo  (8-wave BK=64 GEMM, fp32 out)
    gemm_bb<float, 1, 0><<<dim3(32, 16), 512, 0, stream>>>(Kb, wob, out, bo, (int)MTOT, D_MODEL, D_MODEL);
  } else {
    // ---------------- PER-BATCH PATH (16 MB ws) ----------------
    bf16* Kb  = (bf16*)d_ws;                         // [2048][2048] 8 MB
    bf16* VTb = Kb + (size_t)BROWS * D_MODEL;        // [2048][2048] 8 MB

    for (int b = 0; b < BATCH; b++) {
      const float* xb   = x   + (size_t)b * BROWS * D_MODEL;
      float*       outb = out + (size_t)b * BROWS * D_MODEL;
      bf16*        sb   = (bf16*)outb;               // Lt, then Q/ctx

      gemm_nt<float, float, bf16, 0, 0><<<dim3(16, 2),  256, 0, stream>>>(xb, wdkv, sb,  nullptr, BROWS, LATENT,  D_MODEL);
      gemm_nt<bf16,  float, bf16, 0, 0><<<dim3(16, 16), 256, 0, stream>>>(sb, wuk,  Kb,  nullptr, BROWS, D_MODEL, LATENT);
      gemm_nt<bf16,  float, bf16, 0, 1><<<dim3(16, 16), 256, 0, stream>>>(sb, wuv,  VTb, nullptr, BROWS, D_MODEL, LATENT);
      gemm_nt<float, float, bf16, 0, 0><<<dim3(16, 16), 256, 0, stream>>>(xb, wq,   sb,  nullptr, BROWS, D_MODEL, D_MODEL);

      rope_kernel<<<(BROWS * NHEAD * 8) / 256, 256, 0, stream>>>(sb, Kb);

      flash_attn<<<dim3(256), 256, 0, stream>>>(sb, Kb, VTb, sb, BROWS);

      hipMemcpyAsync(Kb, sb, (size_t)BROWS * D_MODEL * sizeof(bf16),
                     hipMemcpyDeviceToDevice, stream);
      gemm_nt<bf16, float, float, 1, 0><<<dim3(16, 16), 256, 0, stream>>>(Kb, wo, outb, bo, BROWS, D_MODEL, D_MODEL);
    }
  }
}

// Round 15
// 347.149 us; speedup vs baseline: 1.0264x; 1.0264x over previous
//
#include <hip/hip_runtime.h>
#include <hip/hip_bf16.h>

typedef __bf16 bf16;
typedef __bf16 bf16x8 __attribute__((ext_vector_type(8)));
typedef __bf16 bf16x4 __attribute__((ext_vector_type(4)));
typedef float  f32x4  __attribute__((ext_vector_type(4)));
typedef float  f32x16 __attribute__((ext_vector_type(16)));
typedef unsigned int u32x4 __attribute__((ext_vector_type(4)));

#define D_MODEL 2048
#define SEQ     2048
#define BATCH   2
#define NHEAD   16
#define HDIM    128
#define LATENT  256
#define BROWS   SEQ            // rows per batch = 2048

typedef __attribute__((address_space(1))) void gvoid;
typedef __attribute__((address_space(3))) void svoid;

__device__ __forceinline__ void gld16(const bf16* g, bf16* l) {
  // async global->LDS, 16B per lane; LDS dest must be lane-linear (it is).
  __builtin_amdgcn_global_load_lds((gvoid*)(void*)g, (svoid*)l, 16, 0, 0);
}

__device__ __forceinline__ f32x4 mfma16(bf16x8 a, bf16x8 b, f32x4 c) {
  return __builtin_amdgcn_mfma_f32_16x16x32_bf16(a, b, c, 0, 0, 0);
}
__device__ __forceinline__ f32x16 mfma32(bf16x8 a, bf16x8 b, f32x16 c) {
  return __builtin_amdgcn_mfma_f32_32x32x16_bf16(a, b, c, 0, 0, 0);
}

__device__ __forceinline__ unsigned cvt_pk_bf16(float lo, float hi) {
  unsigned r;
  asm("v_cvt_pk_bf16_f32 %0, %1, %2" : "=v"(r) : "v"(lo), "v"(hi));
  return r;
}

// Integer-bit NaN/Inf firewall (cannot be folded by fast-math).
__device__ __forceinline__ float fw(float v) {
  union { float f; unsigned u; } x; x.f = v;
  if ((x.u & 0x7f800000u) == 0x7f800000u) return 0.f;
  return v;
}

template<typename T>
__device__ __forceinline__ bf16x8 ld_cvt8(const T* p);
template<>
__device__ __forceinline__ bf16x8 ld_cvt8<float>(const float* p) {
  const float4 a = *(const float4*)p;
  const float4 b = *(const float4*)(p + 4);
  bf16x8 r;
  r[0] = (bf16)a.x; r[1] = (bf16)a.y; r[2] = (bf16)a.z; r[3] = (bf16)a.w;
  r[4] = (bf16)b.x; r[5] = (bf16)b.y; r[6] = (bf16)b.z; r[7] = (bf16)b.w;
  return r;
}
template<>
__device__ __forceinline__ bf16x8 ld_cvt8<bf16>(const bf16* p) {
  return *(const bf16x8*)p;
}

template<typename TC>
__device__ __forceinline__ void st_c(TC* p, float v);
template<> __device__ __forceinline__ void st_c<bf16>(bf16* p, float v)   { *p = (bf16)v; }
template<> __device__ __forceinline__ void st_c<float>(float* p, float v) { *p = v; }

// ---------------------------------------------------------------------------
// fp32 -> bf16 conversion, 8 elems/thread (float4 x2 -> bf16x8 store).
// ---------------------------------------------------------------------------
__global__ __launch_bounds__(256)
void cvt_bf16(const float* __restrict__ in, bf16* __restrict__ out, int n8)
{
  int i = blockIdx.x * 256 + threadIdx.x;
  if (i >= n8) return;
  const float4 a = ((const float4*)in)[2 * i];
  const float4 b = ((const float4*)in)[2 * i + 1];
  bf16x8 r;
  r[0] = (bf16)a.x; r[1] = (bf16)a.y; r[2] = (bf16)a.z; r[3] = (bf16)a.w;
  r[4] = (bf16)b.x; r[5] = (bf16)b.y; r[6] = (bf16)b.z; r[7] = (bf16)b.w;
  ((bf16x8*)out)[i] = r;
}

// Fused two-tensor conversion (one launch for x and wq).
__global__ __launch_bounds__(256)
void cvt2_bf16(const float* __restrict__ inA, bf16* __restrict__ outA, int n8A,
               const float* __restrict__ inB, bf16* __restrict__ outB, int n8B)
{
  int i = blockIdx.x * 256 + threadIdx.x;
  const float* in; bf16* out; int k;
  if (i < n8A) { in = inA; out = outA; k = i; }
  else {
    k = i - n8A;
    if (k >= n8B) return;
    in = inB; out = outB;
  }
  const float4 a = ((const float4*)in)[2 * k];
  const float4 b = ((const float4*)in)[2 * k + 1];
  bf16x8 r;
  r[0] = (bf16)a.x; r[1] = (bf16)a.y; r[2] = (bf16)a.z; r[3] = (bf16)a.w;
  r[4] = (bf16)b.x; r[5] = (bf16)b.y; r[6] = (bf16)b.z; r[7] = (bf16)b.w;
  ((bf16x8*)out)[k] = r;
}

// Fused wo-conversion + 16MB ctx copy (one launch; both memory-bound).
__global__ __launch_bounds__(256)
void cvt_copy(const float* __restrict__ wo, bf16* __restrict__ wob, int n8w,
              const bf16* __restrict__ src, bf16* __restrict__ dst, int n8c)
{
  int i = blockIdx.x * 256 + threadIdx.x;
  if (i < n8w) {
    const float4 a = ((const float4*)wo)[2 * i];
    const float4 b = ((const float4*)wo)[2 * i + 1];
    bf16x8 r;
    r[0] = (bf16)a.x; r[1] = (bf16)a.y; r[2] = (bf16)a.z; r[3] = (bf16)a.w;
    r[4] = (bf16)b.x; r[5] = (bf16)b.y; r[6] = (bf16)b.z; r[7] = (bf16)b.w;
    ((bf16x8*)wob)[i] = r;
  } else {
    int k = i - n8w;
    if (k >= n8c) return;
    ((bf16x8*)dst)[k] = ((const bf16x8*)src)[k];
  }
}

// ---------------------------------------------------------------------------
// Legacy reg-staged GEMM (kept for the per-batch fallback path).
// C[M][N] = A[M][K] @ W[N][K]^T (+ bias[col]). TRANSC=1 stores C^T (ld=M).
// ---------------------------------------------------------------------------
template<typename TA, typename TW, typename TC, int BIAS, int TRANSC>
__global__ __launch_bounds__(256)
void gemm_nt(const TA* __restrict__ A, const TW* __restrict__ W,
             TC* __restrict__ C, const float* __restrict__ bias,
             int M, int N, int K)
{
  const int t    = threadIdx.x;
  const int wave = t >> 6, lane = t & 63;
  const int quad = lane >> 4, l16 = lane & 15;
  const int wr = (wave >> 1) * 64, wc = (wave & 1) * 64;
  const int am0 = blockIdx.x * 128;
  const int bn0 = blockIdx.y * 128;

  __shared__ __align__(16) bf16 As[128][40];
  __shared__ __align__(16) bf16 Bs[128][40];

  const f32x4 fzero = {0.f, 0.f, 0.f, 0.f};
  f32x4 acc[4][4];
#pragma unroll
  for (int i = 0; i < 4; i++)
#pragma unroll
    for (int j = 0; j < 4; j++) acc[i][j] = fzero;

  const int srow = t >> 2;
  const int scol = (t & 3) * 8;

  for (int k0 = 0; k0 < K; k0 += 32) {
#pragma unroll
    for (int c = 0; c < 2; c++) {
      int row = srow + c * 64;
      *(bf16x8*)(&As[row][scol]) =
        ld_cvt8<TA>(A + (size_t)(am0 + row) * K + k0 + scol);
      *(bf16x8*)(&Bs[row][scol]) =
        ld_cvt8<TW>(W + (size_t)(bn0 + row) * K + k0 + scol);
    }
    __syncthreads();

    bf16x8 af[4], bfr[4];
#pragma unroll
    for (int i = 0; i < 4; i++)
      af[i]  = *(const bf16x8*)(&As[wr + i*16 + l16][quad*8]);
#pragma unroll
    for (int j = 0; j < 4; j++)
      bfr[j] = *(const bf16x8*)(&Bs[wc + j*16 + l16][quad*8]);
#pragma unroll
    for (int i = 0; i < 4; i++)
#pragma unroll
      for (int j = 0; j < 4; j++)
        acc[i][j] = mfma16(af[i], bfr[j], acc[i][j]);
    __syncthreads();
  }

#pragma unroll
  for (int i = 0; i < 4; i++) {
#pragma unroll
    for (int j = 0; j < 4; j++) {
      int col = bn0 + wc + j*16 + l16;
      float bv = 0.f;
      if (BIAS) bv = bias[col];
#pragma unroll
      for (int r = 0; r < 4; r++) {
        int row = am0 + wr + i*16 + quad*4 + r;   // C/D: col=lane&15, row=quad*4+reg
        if (TRANSC)
          st_c<TC>(&C[(size_t)col * M + row], fw(acc[i][j][r] + bv));
        else
          st_c<TC>(&C[(size_t)row * N + col], fw(acc[i][j][r] + bv));
      }
    }
  }
}

// ---------------------------------------------------------------------------
// m97-structure GEMM, 8-WAVE, BK=32: A,W bf16 via global_load_lds into LINEAR
// LDS. 128x128 tile, 512 threads / 8 waves (each wave 64x32 = 4x2 MFMA).
// 2 blocks/CU x 8 waves = 4 waves/SIMD (r10: -17us vs 4-wave).
// BK axis CLOSED: BK=64 regressed +11us total (r14) -- larger LDS + 4 staging
// ops/thread lengthen the drain without an overlap partner (m132 precedent).
// Staging: 1 A + 1 B chunk per thread.
// ---------------------------------------------------------------------------
template<typename TC, int BIAS, int TRANSC>
__global__ __launch_bounds__(512, 4)
void gemm_bb(const bf16* __restrict__ A, const bf16* __restrict__ W,
             TC* __restrict__ C, const float* __restrict__ bias,
             int M, int N, int K)
{
  const int t    = threadIdx.x;
  const int wave = t >> 6, lane = t & 63;
  const int quad = lane >> 4, l16 = lane & 15;
  const int wr = (wave >> 2) * 64, wc = (wave & 3) * 32;
  const int am0 = blockIdx.x * 128;
  const int bn0 = blockIdx.y * 128;

  __shared__ __align__(16) bf16 As[128 * 32];
  __shared__ __align__(16) bf16 Bs[128 * 32];

  const f32x4 fzero = {0.f, 0.f, 0.f, 0.f};
  f32x4 acc[4][2];
#pragma unroll
  for (int i = 0; i < 4; i++)
#pragma unroll
    for (int j = 0; j < 2; j++) acc[i][j] = fzero;

  const int srow = t >> 2;          // 0..127
  const int scol = (t & 3) * 8;

  for (int k0 = 0; k0 < K; k0 += 32) {
    gld16(A + (size_t)(am0 + srow) * K + k0 + scol, As + t * 8);
    gld16(W + (size_t)(bn0 + srow) * K + k0 + scol, Bs + t * 8);
    __syncthreads();                  // compiler drains vmcnt before barrier

    bf16x8 af[4], bfr[2];
#pragma unroll
    for (int i = 0; i < 4; i++)
      af[i]  = *(const bf16x8*)(As + (size_t)(wr + i*16 + l16) * 32 + quad * 8);
#pragma unroll
    for (int j = 0; j < 2; j++)
      bfr[j] = *(const bf16x8*)(Bs + (size_t)(wc + j*16 + l16) * 32 + quad * 8);
#pragma unroll
    for (int i = 0; i < 4; i++)
#pragma unroll
      for (int j = 0; j < 2; j++)
        acc[i][j] = mfma16(af[i], bfr[j], acc[i][j]);
    __syncthreads();
  }

#pragma unroll
  for (int i = 0; i < 4; i++) {
#pragma unroll
    for (int j = 0; j < 2; j++) {
      int col = bn0 + wc + j*16 + l16;
      float bv = 0.f;
      if (BIAS) bv = bias[col];
#pragma unroll
      for (int r = 0; r < 4; r++) {
        int row = am0 + wr + i*16 + quad*4 + r;
        if (TRANSC)
          st_c<TC>(&C[(size_t)col * M + row], fw(acc[i][j][r] + bv));
        else
          st_c<TC>(&C[(size_t)row * N + col], fw(acc[i][j][r] + bv));
      }
    }
  }
}

// ---------------------------------------------------------------------------
// Fused K+V up-projection, 8-WAVE, BK=32: grid (M/128, N/128, 2). z=0 ->
// K = Lt @ wuk^T (row-major Ck); z=1 -> V^T (Cv, ld=M). A bf16 via
// global_load_lds (linear); W fp32 reg-staged+cvt (padded LDS).
// 1024 blocks = 4 blocks/CU; halves the launch tail vs two launches.
// ---------------------------------------------------------------------------
__global__ __launch_bounds__(512, 4)
void gemm_kv(const bf16* __restrict__ A,
             const float* __restrict__ Wk, const float* __restrict__ Wv,
             bf16* __restrict__ Ck, bf16* __restrict__ Cv,
             int M, int N, int K)
{
  const int z    = blockIdx.z;
  const float* W = z ? Wv : Wk;
  const int t    = threadIdx.x;
  const int wave = t >> 6, lane = t & 63;
  const int quad = lane >> 4, l16 = lane & 15;
  const int wr = (wave >> 2) * 64, wc = (wave & 3) * 32;
  const int am0 = blockIdx.x * 128;
  const int bn0 = blockIdx.y * 128;

  __shared__ __align__(16) bf16 As[128 * 32];
  __shared__ __align__(16) bf16 Bs[128][40];

  const f32x4 fzero = {0.f, 0.f, 0.f, 0.f};
  f32x4 acc[4][2];
#pragma unroll
  for (int i = 0; i < 4; i++)
#pragma unroll
    for (int j = 0; j < 2; j++) acc[i][j] = fzero;

  const int srow = t >> 2;          // 0..127
  const int scol = (t & 3) * 8;

  for (int k0 = 0; k0 < K; k0 += 32) {
    gld16(A + (size_t)(am0 + srow) * K + k0 + scol, As + t * 8);
    *(bf16x8*)(&Bs[srow][scol]) =
      ld_cvt8<float>(W + (size_t)(bn0 + srow) * K + k0 + scol);
    __syncthreads();

    bf16x8 af[4], bfr[2];
#pragma unroll
    for (int i = 0; i < 4; i++)
      af[i]  = *(const bf16x8*)(As + (size_t)(wr + i*16 + l16) * 32 + quad * 8);
#pragma unroll
    for (int j = 0; j < 2; j++)
      bfr[j] = *(const bf16x8*)(&Bs[wc + j*16 + l16][quad*8]);
#pragma unroll
    for (int i = 0; i < 4; i++)
#pragma unroll
      for (int j = 0; j < 2; j++)
        acc[i][j] = mfma16(af[i], bfr[j], acc[i][j]);
    __syncthreads();
  }

#pragma unroll
  for (int i = 0; i < 4; i++) {
#pragma unroll
    for (int j = 0; j < 2; j++) {
      int col  = bn0 + wc + j*16 + l16;
      int row0 = am0 + wr + i*16 + quad*4;
      if (z) {                         // V^T: 4 consecutive rows -> bf16x4
        bf16x4 o4;
#pragma unroll
        for (int r = 0; r < 4; r++) o4[r] = (bf16)fw(acc[i][j][r]);
        *(bf16x4*)(Cv + (size_t)col * M + row0) = o4;
      } else {                         // K: row-major scalar stores
#pragma unroll
        for (int r = 0; r < 4; r++)
          Ck[(size_t)(row0 + r) * N + col] = (bf16)fw(acc[i][j][r]);
      }
    }
  }
}

// ---------------------------------------------------------------------------
// Split-K GEMM, 8-WAVE, BK=32, for the latent projection (M=4096, N=256,
// K=2048): grid (M/128, N/128, SPLITK). Each z-slice computes a K-chunk
// partial into Cp[z][M][N] (f32). Deterministic; reduce_sk sums.
// ---------------------------------------------------------------------------
template<int SPLITK>
__global__ __launch_bounds__(512, 4)
void gemm_bf_sk(const bf16* __restrict__ A, const float* __restrict__ W,
                float* __restrict__ Cp, int M, int N, int K)
{
  const int t    = threadIdx.x;
  const int wave = t >> 6, lane = t & 63;
  const int quad = lane >> 4, l16 = lane & 15;
  const int wr = (wave >> 2) * 64, wc = (wave & 3) * 32;
  const int am0 = blockIdx.x * 128;
  const int bn0 = blockIdx.y * 128;
  const int kbeg = blockIdx.z * (K / SPLITK);
  const int kend = kbeg + K / SPLITK;

  __shared__ __align__(16) bf16 As[128 * 32];
  __shared__ __align__(16) bf16 Bs[128][40];

  const f32x4 fzero = {0.f, 0.f, 0.f, 0.f};
  f32x4 acc[4][2];
#pragma unroll
  for (int i = 0; i < 4; i++)
#pragma unroll
    for (int j = 0; j < 2; j++) acc[i][j] = fzero;

  const int srow = t >> 2;
  const int scol = (t & 3) * 8;

  for (int k0 = kbeg; k0 < kend; k0 += 32) {
    gld16(A + (size_t)(am0 + srow) * K + k0 + scol, As + t * 8);
    *(bf16x8*)(&Bs[srow][scol]) =
      ld_cvt8<float>(W + (size_t)(bn0 + srow) * K + k0 + scol);
    __syncthreads();

    bf16x8 af[4], bfr[2];
#pragma unroll
    for (int i = 0; i < 4; i++)
      af[i]  = *(const bf16x8*)(As + (size_t)(wr + i*16 + l16) * 32 + quad * 8);
#pragma unroll
    for (int j = 0; j < 2; j++)
      bfr[j] = *(const bf16x8*)(&Bs[wc + j*16 + l16][quad*8]);
#pragma unroll
    for (int i = 0; i < 4; i++)
#pragma unroll
      for (int j = 0; j < 2; j++)
        acc[i][j] = mfma16(af[i], bfr[j], acc[i][j]);
    __syncthreads();
  }

  float* Cb = Cp + (size_t)blockIdx.z * M * N;
#pragma unroll
  for (int i = 0; i < 4; i++)
#pragma unroll
    for (int j = 0; j < 2; j++) {
      int col = bn0 + wc + j*16 + l16;
#pragma unroll
      for (int r = 0; r < 4; r++) {
        int row = am0 + wr + i*16 + quad*4 + r;
        Cb[(size_t)row * N + col] = acc[i][j][r];
      }
    }
}

// Sum SPLITK f32 partials -> bf16 out. 4 outputs/thread (float4 loads).
template<int SPLITK>
__global__ __launch_bounds__(256)
void reduce_sk(const float* __restrict__ Cp, bf16* __restrict__ out, int MN)
{
  int i4 = (blockIdx.x * 256 + threadIdx.x) * 4;
  if (i4 >= MN) return;
  float4 s = *(const float4*)(Cp + i4);
#pragma unroll
  for (int k = 1; k < SPLITK; k++) {
    float4 p = *(const float4*)(Cp + (size_t)k * MN + i4);
    s.x += p.x; s.y += p.y; s.z += p.z; s.w += p.w;
  }
  bf16x4 o;
  o[0] = (bf16)fw(s.x); o[1] = (bf16)fw(s.y);
  o[2] = (bf16)fw(s.z); o[3] = (bf16)fw(s.w);
  *(bf16x4*)(out + i4) = o;
}

// ---------------------------------------------------------------------------
// RoPE in place on Q and K, layout [Mtot][2048]; seq pos = row & 2047.
// Vectorized: thread handles 8 consecutive j (bf16x8 loads/stores, 16B).
// Threads = Mtot * 16 heads * 8 jgroups.
// ---------------------------------------------------------------------------
__global__ __launch_bounds__(256)
void rope_kernel(bf16* __restrict__ Q, bf16* __restrict__ Kr)
{
  int idx = blockIdx.x * 256 + threadIdx.x;
  int jg  = idx & 7;
  int h   = (idx >> 3) & 15;
  int row = idx >> 7;
  int s   = row & (SEQ - 1);

  size_t base = (size_t)row * D_MODEL + h * HDIM + jg * 8;
  bf16x8 q1 = *(const bf16x8*)(Q  + base);
  bf16x8 q2 = *(const bf16x8*)(Q  + base + 64);
  bf16x8 k1 = *(const bf16x8*)(Kr + base);
  bf16x8 k2 = *(const bf16x8*)(Kr + base + 64);
  bf16x8 q1o, q2o, k1o, k2o;
#pragma unroll
  for (int u = 0; u < 8; u++) {
    int j = jg * 8 + u;
    float invf = exp2f(-0.2076205059304601f * (float)j);  // 10000^(-j/64)
    float ang  = (float)s * invf;
    float c, si;
    sincosf(ang, &si, &c);
    float a1 = (float)q1[u], a2 = (float)q2[u];
    q1o[u] = (bf16)(a1 * c - a2 * si);
    q2o[u] = (bf16)(a2 * c + a1 * si);
    float b1 = (float)k1[u], b2 = (float)k2[u];
    k1o[u] = (bf16)(b1 * c - b2 * si);
    k2o[u] = (bf16)(b2 * c + b1 * si);
  }
  *(bf16x8*)(Q  + base)      = q1o;
  *(bf16x8*)(Q  + base + 64) = q2o;
  *(bf16x8*)(Kr + base)      = k1o;
  *(bf16x8*)(Kr + base + 64) = k2o;
}

// ---------------------------------------------------------------------------
// Causal flash attention v2 (best measured: 76.2-81.6us; KVBLK=64).
// CLOSED factor matrix r3-r12: setprio -7us; XCD decode + ls[4] -6us;
// 8-wave merge -10us; dbuf -4us; KVBLK=128 -36us (VGPR spill). KVBLK=64
// is exactly the tile size whose full K/V prefetch fits in registers.
// Swapped-operand 32x32x16 MFMA + fully in-register softmax (T12).
// Block = (128 q-rows, head, batch); 4 waves x 32 q-rows; KV tile 64,
// single-buffer LDS, commit -> sync -> prefetch-issue -> compute -> sync.
// Complementary-qt pairing: blocks L and L+256 get qt=a / 15-a.
// O may alias Q (block-local region).
// ---------------------------------------------------------------------------
__global__ __launch_bounds__(256, 2)
void flash_attn(const bf16* __restrict__ Q, const bf16* __restrict__ Kc,
                const bf16* __restrict__ VT, bf16* __restrict__ O, int ldVT)
{
  const int L    = blockIdx.x;
  const int half = L >> 8;            // 0 or 1 (full path); 0 (per-batch)
  const int Mn   = L & 255;
  const int h    = Mn >> 4;
  const int a    = Mn & 15;
  const int qt   = half ? 15 - a : a; // complementary pairing
  const int b    = half;
  const int t    = threadIdx.x;
  const int wave = t >> 6, lane = t & 63;
  const int m31  = lane & 31, hi = lane >> 5;
  const int rowbase = b * SEQ;

  __shared__ __align__(16) bf16 Ks[64 * 128];   // 16 KB, rows 256B, XOR-swz
  __shared__ __align__(16) bf16 Vs[128 * 64];   // 16 KB, V^T rows 128B, XOR-swz

  // Q fragments (B-operand): lane holds Q[q=m31][d = dk*16 + hi*8 + j]
  bf16x8 qf[8];
  {
    const bf16* qp = Q + (size_t)(rowbase + qt*128 + wave*32 + m31) * D_MODEL
                   + h * HDIM + hi * 8;
#pragma unroll
    for (int dk = 0; dk < 8; dk++)
      qf[dk] = *(const bf16x8*)(qp + dk * 16);
  }

  f32x16 oacc[4];                     // C[m=d][n=q]: d = db*32 + crow(r,hi)
#pragma unroll
  for (int db = 0; db < 4; db++)
#pragma unroll
    for (int i = 0; i < 16; i++) oacc[db][i] = 0.f;
  float lsum = 0.f;

  // scale folded into exp2 domain: log2(e)/sqrt(128)
  const float SC2 = 0.12752051581562927f;

  const int ktmax = 2*qt + 1;
  const bf16* kbase0 = Kc + (size_t)rowbase * D_MODEL + h * HDIM;
  const bf16* vbase0 = VT + (size_t)(h*HDIM) * ldVT + rowbase;

  bf16x8 kr[4], vr[4];
#pragma unroll
  for (int c = 0; c < 4; c++) {          // prefetch tile 0
    int e = c*256 + t;
    kr[c] = *(const bf16x8*)(kbase0 + (size_t)(e >> 4) * D_MODEL + (e & 15) * 8);
    vr[c] = *(const bf16x8*)(vbase0 + (size_t)(e >> 3) * ldVT + (e & 7) * 8);
  }

  for (int kt = 0; kt <= ktmax; kt++) {
    // ---- commit prefetched tile to LDS (XOR-swizzled chunks) ----
#pragma unroll
    for (int c = 0; c < 4; c++) {
      int e = c*256 + t;
      int krow = e >> 4, kch = e & 15;
      *(bf16x8*)(Ks + krow * 128 + ((kch ^ (krow & 7)) * 8)) = kr[c];
      int vrow = e >> 3, vch = e & 7;
      *(bf16x8*)(Vs + vrow * 64  + ((vch ^ (vrow & 7)) * 8)) = vr[c];
    }
    __syncthreads();

    // ---- prefetch next tile into regs (overlaps compute below) ----
    if (kt < ktmax) {
      const bf16* kb = kbase0 + (size_t)((kt+1)*64) * D_MODEL;
      const bf16* vb = vbase0 + (kt+1)*64;
#pragma unroll
      for (int c = 0; c < 4; c++) {
        int e = c*256 + t;
        kr[c] = *(const bf16x8*)(kb + (size_t)(e >> 4) * D_MODEL + (e & 15) * 8);
        vr[c] = *(const bf16x8*)(vb + (size_t)(e >> 3) * ldVT + (e & 7) * 8);
      }
    }

    const int kvoff = kt*64 - qt*128;    // >=0 only for the 2 diagonal tiles
    // wave fully masked for this tile? (kvoff==64 and q_local <= 63)
    const bool activ = (kvoff < 0) | (kvoff <= wave*32 + 31);

    if (activ) {
      unsigned pb[4][4];                 // [kc 16-k chunk][B-frag dword]
#pragma unroll
      for (int kb = 0; kb < 2; kb++) {
        // ---- S^T = K Q^T (32k x 32q) ----
        f32x16 s;
#pragma unroll
        for (int i = 0; i < 16; i++) s[i] = 0.f;
        const int krow = kb*32 + m31;
        const bf16* ksrow = Ks + krow * 128;
        const int swz = (krow & 7);
#pragma unroll
        for (int dk = 0; dk < 8; dk++) {
          bf16x8 kf = *(const bf16x8*)(ksrow + (((dk*2 + hi) ^ swz) * 8));
          s = mfma32(kf, qf[dk], s);
        }

        // ---- static-max softmax numerator, lane-local ----
        float p[16];
        const int kq = kvoff + kb*32 + 4*hi - (wave*32 + m31);  // k - q offset
#pragma unroll
        for (int r = 0; r < 16; r++) {
          float v = s[r] * SC2;
          const int kk = (r & 3) + 8 * (r >> 2);
          if (kvoff >= 0 && (kq + kk) > 0) v = -1e30f;
          float e2 = exp2f(v);
          lsum += e2;
          p[r] = e2;
        }

        // ---- pack to PV B-operand: cvt_pk pairs + permlane32 half-swap ----
#pragma unroll
        for (int c = 0; c < 2; c++) {
          unsigned a0 = cvt_pk_bf16(p[(2*c)*4 + 0],   p[(2*c)*4 + 1]);
          unsigned a1 = cvt_pk_bf16(p[(2*c)*4 + 2],   p[(2*c)*4 + 3]);
          unsigned b0 = cvt_pk_bf16(p[(2*c+1)*4 + 0], p[(2*c+1)*4 + 1]);
          unsigned b1 = cvt_pk_bf16(p[(2*c+1)*4 + 2], p[(2*c+1)*4 + 3]);
          asm("v_permlane32_swap_b32 %0, %1" : "+v"(a0), "+v"(b0));
          asm("v_permlane32_swap_b32 %0, %1" : "+v"(a1), "+v"(b1));
          pb[kb*2 + c][0] = a0; pb[kb*2 + c][1] = a1;
          pb[kb*2 + c][2] = b0; pb[kb*2 + c][3] = b1;
        }
      }

      // ---- O^T += V^T P^T : C[m=d][n=q], A = V^T frags from LDS ----
#pragma unroll
      for (int db = 0; db < 4; db++) {
        const int vrow = db*32 + m31;
        const bf16* vsrow = Vs + vrow * 64;
        const int swz = (vrow & 7);
#pragma unroll
        for (int kc = 0; kc < 4; kc++) {
          bf16x8 vf = *(const bf16x8*)(vsrow + (((kc*2 + hi) ^ swz) * 8));
          u32x4 w = {pb[kc][0], pb[kc][1], pb[kc][2], pb[kc][3]};
          oacc[db] = mfma32(vf, __builtin_bit_cast(bf16x8, w), oacc[db]);
        }
      }
    }
    __syncthreads();
  }

  // ---- epilogue: combine half-row sums, scale, store (8B packed) ----
  const float ltot = lsum + __shfl_xor(lsum, 32, 64);
  const float invl = 1.f / ltot;
  const size_t ob = (size_t)(rowbase + qt*128 + wave*32 + m31) * D_MODEL + h * HDIM;
#pragma unroll
  for (int db = 0; db < 4; db++) {
#pragma unroll
    for (int q2 = 0; q2 < 4; q2++) {
      bf16x4 o4;
#pragma unroll
      for (int rr = 0; rr < 4; rr++)
        o4[rr] = (bf16)(oacc[db][q2*4 + rr] * invl);   // d = db*32+q2*8+hi*4+rr
      *(bf16x4*)(O + ob + db*32 + q2*8 + hi*4) = o4;
    }
  }
}

// ---------------------------------------------------------------------------
// Inputs FP32, output FP32. Path chosen by ws_size (deterministic, graph-safe).
//
// Full-path ws layout (35.65 MB == NEED_FULL, aliasing by liveness):
//   [0,16MB)  Kb   (K bf16)   <- holds wqb (8MB) until Q-GEMM, then split-K
//                                partials [0,32MB) until reduce_sk
//   [16,32MB) VTb  (V^T bf16) <- partials overlap; later wob (8MB) after attn
//   [32,34MB) Lt   (latent bf16)
// d_out scratch: [0,16MB) Q/ctx bf16; [16,32MB) xb (x in bf16, dead before
// the final fp32 output write).
// ---------------------------------------------------------------------------
extern "C" void kernel_launch(void* const* d_in, const int* in_sizes, int n_in,
                              void* d_out, int out_size, void* d_ws, size_t ws_size,
                              hipStream_t stream)
{
  const float* x    = (const float*)d_in[0];
  const float* wq   = (const float*)d_in[1];
  const float* wdkv = (const float*)d_in[2];
  const float* wuk  = (const float*)d_in[3];
  const float* wuv  = (const float*)d_in[4];
  const float* wo   = (const float*)d_in[5];
  const float* bo   = (const float*)d_in[6];
  float* out = (float*)d_out;

  const size_t MTOT = (size_t)BATCH * BROWS;              // 4096
  const size_t NEED_FULL = (MTOT * D_MODEL + (size_t)D_MODEL * MTOT
                          + MTOT * LATENT) * sizeof(bf16);  // 35.7 MB

  if (ws_size >= NEED_FULL) {
    // ---------------- FULL-BATCH PATH ----------------
    bf16* Kb  = (bf16*)d_ws;                         // [4096][2048]
    bf16* VTb = Kb  + MTOT * D_MODEL;                // [2048][4096]
    bf16* Lt  = VTb + (size_t)D_MODEL * MTOT;        // [4096][256]
    bf16* wqb = Kb;                                  // aliases Kb (8 MB)
    bf16* wob = VTb;                                 // aliases VTb (8 MB)
    float* Pp = (float*)d_ws;                        // split-K partials, 32 MB
    bf16* sb  = (bf16*)out;                          // Q/ctx bf16, d_out[0,16M)
    bf16* xb  = sb + MTOT * D_MODEL;                 // x bf16,    d_out[16,32M)

    const int n8x = (int)(MTOT * D_MODEL / 8);                 // 1048576
    const int n8w = (int)((size_t)D_MODEL * D_MODEL / 8);      // 524288

    // 1) conversions: x (16MB bf16) and wq (8MB bf16), one fused launch
    cvt2_bf16<<<(n8x + n8w) / 256, 256, 0, stream>>>(x, xb, n8x, wq, wqb, n8w);

    // 2) Q = xb @ wqb^T  (8-wave m97 GEMM) -- must precede partial writes
    gemm_bb<bf16, 0, 0><<<dim3(32, 16), 512, 0, stream>>>(xb, wqb, sb, nullptr, (int)MTOT, D_MODEL, D_MODEL);

    // 3) latent: Lt = xb @ wdkv^T via split-K 8 (partials in dead Kb+VTb)
    gemm_bf_sk<8><<<dim3(32, 2, 8), 512, 0, stream>>>(xb, wdkv, Pp, (int)MTOT, LATENT, D_MODEL);
    reduce_sk<8><<<(int)(MTOT * LATENT / 4 / 256), 256, 0, stream>>>(Pp, Lt, (int)(MTOT * LATENT));
    //    xb, wqb, partials dead from here
    // 4) K and V^T in ONE launch (1024 blocks = 4 blocks/CU)
    gemm_kv<<<dim3(32, 16, 2), 512, 0, stream>>>(Lt, wuk, wuv, Kb, VTb, (int)MTOT, D_MODEL, LATENT);

    rope_kernel<<<(int)(MTOT * NHEAD * 8) / 256, 256, 0, stream>>>(sb, Kb);

    flash_attn<<<dim3(512), 256, 0, stream>>>(sb, Kb, VTb, sb, (int)MTOT);

    // 5) wo -> bf16 into dead VTb region + ctx -> dead Kb region, one launch
    cvt_copy<<<(n8w + n8x) / 256 + 1, 256, 0, stream>>>(wo, wob, n8w, sb, Kb, n8x);

    // 6) out = ctx @ wob^T + bo  (8-wave m97 GEMM, fp32 out)
    gemm_bb<float, 1, 0><<<dim3(32, 16), 512, 0, stream>>>(Kb, wob, out, bo, (int)MTOT, D_MODEL, D_MODEL);
  } else {
    // ---------------- PER-BATCH PATH (16 MB ws) ----------------
    bf16* Kb  = (bf16*)d_ws;                         // [2048][2048] 8 MB
    bf16* VTb = Kb + (size_t)BROWS * D_MODEL;        // [2048][2048] 8 MB

    for (int b = 0; b < BATCH; b++) {
      const float* xb   = x   + (size_t)b * BROWS * D_MODEL;
      float*       outb = out + (size_t)b * BROWS * D_MODEL;
      bf16*        sb   = (bf16*)outb;               // Lt, then Q/ctx

      gemm_nt<float, float, bf16, 0, 0><<<dim3(16, 2),  256, 0, stream>>>(xb, wdkv, sb,  nullptr, BROWS, LATENT,  D_MODEL);
      gemm_nt<bf16,  float, bf16, 0, 0><<<dim3(16, 16), 256, 0, stream>>>(sb, wuk,  Kb,  nullptr, BROWS, D_MODEL, LATENT);
      gemm_nt<bf16,  float, bf16, 0, 1><<<dim3(16, 16), 256, 0, stream>>>(sb, wuv,  VTb, nullptr, BROWS, D_MODEL, LATENT);
      gemm_nt<float, float, bf16, 0, 0><<<dim3(16, 16), 256, 0, stream>>>(xb, wq,   sb,  nullptr, BROWS, D_MODEL, D_MODEL);

      rope_kernel<<<(BROWS * NHEAD * 8) / 256, 256, 0, stream>>>(sb, Kb);

      flash_attn<<<dim3(256), 256, 0, stream>>>(sb, Kb, VTb, sb, BROWS);

      hipMemcpyAsync(Kb, sb, (size_t)BROWS * D_MODEL * sizeof(bf16),
                     hipMemcpyDeviceToDevice, stream);
      gemm_nt<bf16, float, float, 1, 0><<<dim3(16, 16), 256, 0, stream>>>(Kb, wo, outb, bo, BROWS, D_MODEL, D_MODEL);
    }
  }
}

// Round 16
// 336.644 us; speedup vs baseline: 1.0584x; 1.0312x over previous
//
#include <hip/hip_runtime.h>
#include <hip/hip_bf16.h>

typedef __bf16 bf16;
typedef __bf16 bf16x8 __attribute__((ext_vector_type(8)));
typedef __bf16 bf16x4 __attribute__((ext_vector_type(4)));
typedef float  f32x4  __attribute__((ext_vector_type(4)));
typedef float  f32x16 __attribute__((ext_vector_type(16)));
typedef unsigned int u32x4 __attribute__((ext_vector_type(4)));

#define D_MODEL 2048
#define SEQ     2048
#define BATCH   2
#define NHEAD   16
#define HDIM    128
#define LATENT  256
#define BROWS   SEQ            // rows per batch = 2048

typedef __attribute__((address_space(1))) void gvoid;
typedef __attribute__((address_space(3))) void svoid;

__device__ __forceinline__ void gld16(const bf16* g, bf16* l) {
  // async global->LDS, 16B per lane; LDS dest must be lane-linear (it is).
  __builtin_amdgcn_global_load_lds((gvoid*)(void*)g, (svoid*)l, 16, 0, 0);
}

__device__ __forceinline__ f32x4 mfma16(bf16x8 a, bf16x8 b, f32x4 c) {
  return __builtin_amdgcn_mfma_f32_16x16x32_bf16(a, b, c, 0, 0, 0);
}
__device__ __forceinline__ f32x16 mfma32(bf16x8 a, bf16x8 b, f32x16 c) {
  return __builtin_amdgcn_mfma_f32_32x32x16_bf16(a, b, c, 0, 0, 0);
}

__device__ __forceinline__ unsigned cvt_pk_bf16(float lo, float hi) {
  unsigned r;
  asm("v_cvt_pk_bf16_f32 %0, %1, %2" : "=v"(r) : "v"(lo), "v"(hi));
  return r;
}

// Integer-bit NaN/Inf firewall (cannot be folded by fast-math).
__device__ __forceinline__ float fw(float v) {
  union { float f; unsigned u; } x; x.f = v;
  if ((x.u & 0x7f800000u) == 0x7f800000u) return 0.f;
  return v;
}

template<typename T>
__device__ __forceinline__ bf16x8 ld_cvt8(const T* p);
template<>
__device__ __forceinline__ bf16x8 ld_cvt8<float>(const float* p) {
  const float4 a = *(const float4*)p;
  const float4 b = *(const float4*)(p + 4);
  bf16x8 r;
  r[0] = (bf16)a.x; r[1] = (bf16)a.y; r[2] = (bf16)a.z; r[3] = (bf16)a.w;
  r[4] = (bf16)b.x; r[5] = (bf16)b.y; r[6] = (bf16)b.z; r[7] = (bf16)b.w;
  return r;
}
template<>
__device__ __forceinline__ bf16x8 ld_cvt8<bf16>(const bf16* p) {
  return *(const bf16x8*)p;
}

template<typename TC>
__device__ __forceinline__ void st_c(TC* p, float v);
template<> __device__ __forceinline__ void st_c<bf16>(bf16* p, float v)   { *p = (bf16)v; }
template<> __device__ __forceinline__ void st_c<float>(float* p, float v) { *p = v; }

// ---------------------------------------------------------------------------
// fp32 -> bf16 conversion, 8 elems/thread (float4 x2 -> bf16x8 store).
// ---------------------------------------------------------------------------
__global__ __launch_bounds__(256)
void cvt_bf16(const float* __restrict__ in, bf16* __restrict__ out, int n8)
{
  int i = blockIdx.x * 256 + threadIdx.x;
  if (i >= n8) return;
  const float4 a = ((const float4*)in)[2 * i];
  const float4 b = ((const float4*)in)[2 * i + 1];
  bf16x8 r;
  r[0] = (bf16)a.x; r[1] = (bf16)a.y; r[2] = (bf16)a.z; r[3] = (bf16)a.w;
  r[4] = (bf16)b.x; r[5] = (bf16)b.y; r[6] = (bf16)b.z; r[7] = (bf16)b.w;
  ((bf16x8*)out)[i] = r;
}

// Fused two-tensor conversion (one launch for x and wq).
__global__ __launch_bounds__(256)
void cvt2_bf16(const float* __restrict__ inA, bf16* __restrict__ outA, int n8A,
               const float* __restrict__ inB, bf16* __restrict__ outB, int n8B)
{
  int i = blockIdx.x * 256 + threadIdx.x;
  const float* in; bf16* out; int k;
  if (i < n8A) { in = inA; out = outA; k = i; }
  else {
    k = i - n8A;
    if (k >= n8B) return;
    in = inB; out = outB;
  }
  const float4 a = ((const float4*)in)[2 * k];
  const float4 b = ((const float4*)in)[2 * k + 1];
  bf16x8 r;
  r[0] = (bf16)a.x; r[1] = (bf16)a.y; r[2] = (bf16)a.z; r[3] = (bf16)a.w;
  r[4] = (bf16)b.x; r[5] = (bf16)b.y; r[6] = (bf16)b.z; r[7] = (bf16)b.w;
  ((bf16x8*)out)[k] = r;
}

// Fused wo-conversion + 16MB ctx copy (one launch; both memory-bound).
__global__ __launch_bounds__(256)
void cvt_copy(const float* __restrict__ wo, bf16* __restrict__ wob, int n8w,
              const bf16* __restrict__ src, bf16* __restrict__ dst, int n8c)
{
  int i = blockIdx.x * 256 + threadIdx.x;
  if (i < n8w) {
    const float4 a = ((const float4*)wo)[2 * i];
    const float4 b = ((const float4*)wo)[2 * i + 1];
    bf16x8 r;
    r[0] = (bf16)a.x; r[1] = (bf16)a.y; r[2] = (bf16)a.z; r[3] = (bf16)a.w;
    r[4] = (bf16)b.x; r[5] = (bf16)b.y; r[6] = (bf16)b.z; r[7] = (bf16)b.w;
    ((bf16x8*)wob)[i] = r;
  } else {
    int k = i - n8w;
    if (k >= n8c) return;
    ((bf16x8*)dst)[k] = ((const bf16x8*)src)[k];
  }
}

// ---------------------------------------------------------------------------
// Legacy reg-staged GEMM (kept for the per-batch fallback path).
// C[M][N] = A[M][K] @ W[N][K]^T (+ bias[col]). TRANSC=1 stores C^T (ld=M).
// ---------------------------------------------------------------------------
template<typename TA, typename TW, typename TC, int BIAS, int TRANSC>
__global__ __launch_bounds__(256)
void gemm_nt(const TA* __restrict__ A, const TW* __restrict__ W,
             TC* __restrict__ C, const float* __restrict__ bias,
             int M, int N, int K)
{
  const int t    = threadIdx.x;
  const int wave = t >> 6, lane = t & 63;
  const int quad = lane >> 4, l16 = lane & 15;
  const int wr = (wave >> 1) * 64, wc = (wave & 1) * 64;
  const int am0 = blockIdx.x * 128;
  const int bn0 = blockIdx.y * 128;

  __shared__ __align__(16) bf16 As[128][40];
  __shared__ __align__(16) bf16 Bs[128][40];

  const f32x4 fzero = {0.f, 0.f, 0.f, 0.f};
  f32x4 acc[4][4];
#pragma unroll
  for (int i = 0; i < 4; i++)
#pragma unroll
    for (int j = 0; j < 4; j++) acc[i][j] = fzero;

  const int srow = t >> 2;
  const int scol = (t & 3) * 8;

  for (int k0 = 0; k0 < K; k0 += 32) {
#pragma unroll
    for (int c = 0; c < 2; c++) {
      int row = srow + c * 64;
      *(bf16x8*)(&As[row][scol]) =
        ld_cvt8<TA>(A + (size_t)(am0 + row) * K + k0 + scol);
      *(bf16x8*)(&Bs[row][scol]) =
        ld_cvt8<TW>(W + (size_t)(bn0 + row) * K + k0 + scol);
    }
    __syncthreads();

    bf16x8 af[4], bfr[4];
#pragma unroll
    for (int i = 0; i < 4; i++)
      af[i]  = *(const bf16x8*)(&As[wr + i*16 + l16][quad*8]);
#pragma unroll
    for (int j = 0; j < 4; j++)
      bfr[j] = *(const bf16x8*)(&Bs[wc + j*16 + l16][quad*8]);
#pragma unroll
    for (int i = 0; i < 4; i++)
#pragma unroll
      for (int j = 0; j < 4; j++)
        acc[i][j] = mfma16(af[i], bfr[j], acc[i][j]);
    __syncthreads();
  }

#pragma unroll
  for (int i = 0; i < 4; i++) {
#pragma unroll
    for (int j = 0; j < 4; j++) {
      int col = bn0 + wc + j*16 + l16;
      float bv = 0.f;
      if (BIAS) bv = bias[col];
#pragma unroll
      for (int r = 0; r < 4; r++) {
        int row = am0 + wr + i*16 + quad*4 + r;   // C/D: col=lane&15, row=quad*4+reg
        if (TRANSC)
          st_c<TC>(&C[(size_t)col * M + row], fw(acc[i][j][r] + bv));
        else
          st_c<TC>(&C[(size_t)row * N + col], fw(acc[i][j][r] + bv));
      }
    }
  }
}

// ---------------------------------------------------------------------------
// m97-structure GEMM, 8-WAVE, BK=32, optional fused RoPE epilogue.
// ROPE=0: column mapping (wave&3)*32 + j*16 (byte-identical to r13 kernel).
// ROPE=1: column mapping (wave&3)*16 + j*64 -- each wave owns BOTH halves of
//   the rotation pair (jj, jj+64), so acc[i][0][r]/acc[i][1][r] are the pair
//   and RoPE is a pure register rotation at store time (no LDS, no barrier,
//   no separate 64MB rope pass). Coverage & LDS bank pattern identical.
// 2 blocks/CU x 8 waves = 4 waves/SIMD (r10: -17us). BK axis closed (r14).
// ---------------------------------------------------------------------------
template<typename TC, int BIAS, int TRANSC, int ROPE>
__global__ __launch_bounds__(512, 4)
void gemm_bb(const bf16* __restrict__ A, const bf16* __restrict__ W,
             TC* __restrict__ C, const float* __restrict__ bias,
             int M, int N, int K)
{
  const int t    = threadIdx.x;
  const int wave = t >> 6, lane = t & 63;
  const int quad = lane >> 4, l16 = lane & 15;
  const int wr = (wave >> 2) * 64;
  const int w3 = wave & 3;

  const int am0 = blockIdx.x * 128;
  const int bn0 = blockIdx.y * 128;

  __shared__ __align__(16) bf16 As[128 * 32];
  __shared__ __align__(16) bf16 Bs[128 * 32];

  const f32x4 fzero = {0.f, 0.f, 0.f, 0.f};
  f32x4 acc[4][2];
#pragma unroll
  for (int i = 0; i < 4; i++)
#pragma unroll
    for (int j = 0; j < 2; j++) acc[i][j] = fzero;

  const int srow = t >> 2;          // 0..127
  const int scol = (t & 3) * 8;

  for (int k0 = 0; k0 < K; k0 += 32) {
    gld16(A + (size_t)(am0 + srow) * K + k0 + scol, As + t * 8);
    gld16(W + (size_t)(bn0 + srow) * K + k0 + scol, Bs + t * 8);
    __syncthreads();                  // compiler drains vmcnt before barrier

    bf16x8 af[4], bfr[2];
#pragma unroll
    for (int i = 0; i < 4; i++)
      af[i]  = *(const bf16x8*)(As + (size_t)(wr + i*16 + l16) * 32 + quad * 8);
#pragma unroll
    for (int j = 0; j < 2; j++) {
      int brow = ROPE ? (w3*16 + j*64 + l16) : (w3*32 + j*16 + l16);
      bfr[j] = *(const bf16x8*)(Bs + (size_t)brow * 32 + quad * 8);
    }
#pragma unroll
    for (int i = 0; i < 4; i++)
#pragma unroll
      for (int j = 0; j < 2; j++)
        acc[i][j] = mfma16(af[i], bfr[j], acc[i][j]);
    __syncthreads();
  }

  if (ROPE) {
    // Q-proj epilogue with fused RoPE: jj = w3*16+l16 in [0,64); pair is
    // (bn0+jj, bn0+jj+64); head = bn0/128; seq pos s = row & (SEQ-1).
    const int jj = w3*16 + l16;
    const float invf = exp2f(-0.2076205059304601f * (float)jj); // 10000^(-jj/64)
#pragma unroll
    for (int i = 0; i < 4; i++) {
#pragma unroll
      for (int r = 0; r < 4; r++) {
        int row = am0 + wr + i*16 + quad*4 + r;
        int s   = row & (SEQ - 1);
        float cs, si;
        sincosf((float)s * invf, &si, &cs);
        float a0 = acc[i][0][r], a1 = acc[i][1][r];
        st_c<TC>(&C[(size_t)row * N + bn0 + jj],      fw(a0 * cs - a1 * si));
        st_c<TC>(&C[(size_t)row * N + bn0 + jj + 64], fw(a1 * cs + a0 * si));
      }
    }
  } else {
#pragma unroll
    for (int i = 0; i < 4; i++) {
#pragma unroll
      for (int j = 0; j < 2; j++) {
        int col = bn0 + w3*32 + j*16 + l16;
        float bv = 0.f;
        if (BIAS) bv = bias[col];
#pragma unroll
        for (int r = 0; r < 4; r++) {
          int row = am0 + wr + i*16 + quad*4 + r;
          if (TRANSC)
            st_c<TC>(&C[(size_t)col * M + row], fw(acc[i][j][r] + bv));
          else
            st_c<TC>(&C[(size_t)row * N + col], fw(acc[i][j][r] + bv));
        }
      }
    }
  }
}

// ---------------------------------------------------------------------------
// Fused K+V up-projection, 8-WAVE, BK=32, fused RoPE on K: grid
// (M/128, N/128, 2). z=0 -> K = rope(Lt @ wuk^T) row-major; z=1 -> V^T
// (ld=M). Column mapping (wave&3)*16 + j*64 for BOTH z (coverage identical;
// gives z=0 the in-register rotation pair). A bf16 via global_load_lds;
// W fp32 reg-staged+cvt (padded LDS). 1024 blocks = 4 blocks/CU.
// ---------------------------------------------------------------------------
__global__ __launch_bounds__(512, 4)
void gemm_kv(const bf16* __restrict__ A,
             const float* __restrict__ Wk, const float* __restrict__ Wv,
             bf16* __restrict__ Ck, bf16* __restrict__ Cv,
             int M, int N, int K)
{
  const int z    = blockIdx.z;
  const float* W = z ? Wv : Wk;
  const int t    = threadIdx.x;
  const int wave = t >> 6, lane = t & 63;
  const int quad = lane >> 4, l16 = lane & 15;
  const int wr = (wave >> 2) * 64;
  const int w3 = wave & 3;
  const int am0 = blockIdx.x * 128;
  const int bn0 = blockIdx.y * 128;

  __shared__ __align__(16) bf16 As[128 * 32];
  __shared__ __align__(16) bf16 Bs[128][40];

  const f32x4 fzero = {0.f, 0.f, 0.f, 0.f};
  f32x4 acc[4][2];
#pragma unroll
  for (int i = 0; i < 4; i++)
#pragma unroll
    for (int j = 0; j < 2; j++) acc[i][j] = fzero;

  const int srow = t >> 2;          // 0..127
  const int scol = (t & 3) * 8;

  for (int k0 = 0; k0 < K; k0 += 32) {
    gld16(A + (size_t)(am0 + srow) * K + k0 + scol, As + t * 8);
    *(bf16x8*)(&Bs[srow][scol]) =
      ld_cvt8<float>(W + (size_t)(bn0 + srow) * K + k0 + scol);
    __syncthreads();

    bf16x8 af[4], bfr[2];
#pragma unroll
    for (int i = 0; i < 4; i++)
      af[i]  = *(const bf16x8*)(As + (size_t)(wr + i*16 + l16) * 32 + quad * 8);
#pragma unroll
    for (int j = 0; j < 2; j++)
      bfr[j] = *(const bf16x8*)(&Bs[w3*16 + j*64 + l16][quad*8]);
#pragma unroll
    for (int i = 0; i < 4; i++)
#pragma unroll
      for (int j = 0; j < 2; j++)
        acc[i][j] = mfma16(af[i], bfr[j], acc[i][j]);
    __syncthreads();
  }

  if (z == 0) {
    // K with fused RoPE: jj = w3*16+l16; pair cols (bn0+jj, bn0+jj+64).
    const int jj = w3*16 + l16;
    const float invf = exp2f(-0.2076205059304601f * (float)jj);
#pragma unroll
    for (int i = 0; i < 4; i++) {
#pragma unroll
      for (int r = 0; r < 4; r++) {
        int row = am0 + wr + i*16 + quad*4 + r;
        int s   = row & (SEQ - 1);
        float cs, si;
        sincosf((float)s * invf, &si, &cs);
        float a0 = acc[i][0][r], a1 = acc[i][1][r];
        Ck[(size_t)row * N + bn0 + jj]      = (bf16)fw(a0 * cs - a1 * si);
        Ck[(size_t)row * N + bn0 + jj + 64] = (bf16)fw(a1 * cs + a0 * si);
      }
    }
  } else {
    // V^T: 4 consecutive rows -> bf16x4 per (i,j)
#pragma unroll
    for (int i = 0; i < 4; i++) {
#pragma unroll
      for (int j = 0; j < 2; j++) {
        int col  = bn0 + w3*16 + j*64 + l16;
        int row0 = am0 + wr + i*16 + quad*4;
        bf16x4 o4;
#pragma unroll
        for (int r = 0; r < 4; r++) o4[r] = (bf16)fw(acc[i][j][r]);
        *(bf16x4*)(Cv + (size_t)col * M + row0) = o4;
      }
    }
  }
}

// ---------------------------------------------------------------------------
// Split-K GEMM, 8-WAVE, BK=32, for the latent projection (M=4096, N=256,
// K=2048): grid (M/128, N/128, SPLITK). Each z-slice computes a K-chunk
// partial into Cp[z][M][N] (f32). Deterministic; reduce_sk sums.
// ---------------------------------------------------------------------------
template<int SPLITK>
__global__ __launch_bounds__(512, 4)
void gemm_bf_sk(const bf16* __restrict__ A, const float* __restrict__ W,
                float* __restrict__ Cp, int M, int N, int K)
{
  const int t    = threadIdx.x;
  const int wave = t >> 6, lane = t & 63;
  const int quad = lane >> 4, l16 = lane & 15;
  const int wr = (wave >> 2) * 64, wc = (wave & 3) * 32;
  const int am0 = blockIdx.x * 128;
  const int bn0 = blockIdx.y * 128;
  const int kbeg = blockIdx.z * (K / SPLITK);
  const int kend = kbeg + K / SPLITK;

  __shared__ __align__(16) bf16 As[128 * 32];
  __shared__ __align__(16) bf16 Bs[128][40];

  const f32x4 fzero = {0.f, 0.f, 0.f, 0.f};
  f32x4 acc[4][2];
#pragma unroll
  for (int i = 0; i < 4; i++)
#pragma unroll
    for (int j = 0; j < 2; j++) acc[i][j] = fzero;

  const int srow = t >> 2;
  const int scol = (t & 3) * 8;

  for (int k0 = kbeg; k0 < kend; k0 += 32) {
    gld16(A + (size_t)(am0 + srow) * K + k0 + scol, As + t * 8);
    *(bf16x8*)(&Bs[srow][scol]) =
      ld_cvt8<float>(W + (size_t)(bn0 + srow) * K + k0 + scol);
    __syncthreads();

    bf16x8 af[4], bfr[2];
#pragma unroll
    for (int i = 0; i < 4; i++)
      af[i]  = *(const bf16x8*)(As + (size_t)(wr + i*16 + l16) * 32 + quad * 8);
#pragma unroll
    for (int j = 0; j < 2; j++)
      bfr[j] = *(const bf16x8*)(&Bs[wc + j*16 + l16][quad*8]);
#pragma unroll
    for (int i = 0; i < 4; i++)
#pragma unroll
      for (int j = 0; j < 2; j++)
        acc[i][j] = mfma16(af[i], bfr[j], acc[i][j]);
    __syncthreads();
  }

  float* Cb = Cp + (size_t)blockIdx.z * M * N;
#pragma unroll
  for (int i = 0; i < 4; i++)
#pragma unroll
    for (int j = 0; j < 2; j++) {
      int col = bn0 + wc + j*16 + l16;
#pragma unroll
      for (int r = 0; r < 4; r++) {
        int row = am0 + wr + i*16 + quad*4 + r;
        Cb[(size_t)row * N + col] = acc[i][j][r];
      }
    }
}

// Sum SPLITK f32 partials -> bf16 out. 4 outputs/thread (float4 loads).
template<int SPLITK>
__global__ __launch_bounds__(256)
void reduce_sk(const float* __restrict__ Cp, bf16* __restrict__ out, int MN)
{
  int i4 = (blockIdx.x * 256 + threadIdx.x) * 4;
  if (i4 >= MN) return;
  float4 s = *(const float4*)(Cp + i4);
#pragma unroll
  for (int k = 1; k < SPLITK; k++) {
    float4 p = *(const float4*)(Cp + (size_t)k * MN + i4);
    s.x += p.x; s.y += p.y; s.z += p.z; s.w += p.w;
  }
  bf16x4 o;
  o[0] = (bf16)fw(s.x); o[1] = (bf16)fw(s.y);
  o[2] = (bf16)fw(s.z); o[3] = (bf16)fw(s.w);
  *(bf16x4*)(out + i4) = o;
}

// ---------------------------------------------------------------------------
// RoPE in place on Q and K (per-batch fallback path only; the full path fuses
// RoPE into the producing GEMM epilogues).
// ---------------------------------------------------------------------------
__global__ __launch_bounds__(256)
void rope_kernel(bf16* __restrict__ Q, bf16* __restrict__ Kr)
{
  int idx = blockIdx.x * 256 + threadIdx.x;
  int jg  = idx & 7;
  int h   = (idx >> 3) & 15;
  int row = idx >> 7;
  int s   = row & (SEQ - 1);

  size_t base = (size_t)row * D_MODEL + h * HDIM + jg * 8;
  bf16x8 q1 = *(const bf16x8*)(Q  + base);
  bf16x8 q2 = *(const bf16x8*)(Q  + base + 64);
  bf16x8 k1 = *(const bf16x8*)(Kr + base);
  bf16x8 k2 = *(const bf16x8*)(Kr + base + 64);
  bf16x8 q1o, q2o, k1o, k2o;
#pragma unroll
  for (int u = 0; u < 8; u++) {
    int j = jg * 8 + u;
    float invf = exp2f(-0.2076205059304601f * (float)j);  // 10000^(-j/64)
    float ang  = (float)s * invf;
    float c, si;
    sincosf(ang, &si, &c);
    float a1 = (float)q1[u], a2 = (float)q2[u];
    q1o[u] = (bf16)(a1 * c - a2 * si);
    q2o[u] = (bf16)(a2 * c + a1 * si);
    float b1 = (float)k1[u], b2 = (float)k2[u];
    k1o[u] = (bf16)(b1 * c - b2 * si);
    k2o[u] = (bf16)(b2 * c + b1 * si);
  }
  *(bf16x8*)(Q  + base)      = q1o;
  *(bf16x8*)(Q  + base + 64) = q2o;
  *(bf16x8*)(Kr + base)      = k1o;
  *(bf16x8*)(Kr + base + 64) = k2o;
}

// ---------------------------------------------------------------------------
// Causal flash attention v2 (best measured: 76.2-81.6us; KVBLK=64).
// CLOSED factor matrix r3-r12: setprio -7us; XCD decode + ls[4] -6us;
// 8-wave merge -10us; dbuf -4us; KVBLK=128 -36us (VGPR spill). KVBLK=64
// is exactly the tile size whose full K/V prefetch fits in registers.
// Swapped-operand 32x32x16 MFMA + fully in-register softmax (T12).
// Block = (128 q-rows, head, batch); 4 waves x 32 q-rows; KV tile 64,
// single-buffer LDS, commit -> sync -> prefetch-issue -> compute -> sync.
// Complementary-qt pairing: blocks L and L+256 get qt=a / 15-a.
// O may alias Q (block-local region).
// ---------------------------------------------------------------------------
__global__ __launch_bounds__(256, 2)
void flash_attn(const bf16* __restrict__ Q, const bf16* __restrict__ Kc,
                const bf16* __restrict__ VT, bf16* __restrict__ O, int ldVT)
{
  const int L    = blockIdx.x;
  const int half = L >> 8;            // 0 or 1 (full path); 0 (per-batch)
  const int Mn   = L & 255;
  const int h    = Mn >> 4;
  const int a    = Mn & 15;
  const int qt   = half ? 15 - a : a; // complementary pairing
  const int b    = half;
  const int t    = threadIdx.x;
  const int wave = t >> 6, lane = t & 63;
  const int m31  = lane & 31, hi = lane >> 5;
  const int rowbase = b * SEQ;

  __shared__ __align__(16) bf16 Ks[64 * 128];   // 16 KB, rows 256B, XOR-swz
  __shared__ __align__(16) bf16 Vs[128 * 64];   // 16 KB, V^T rows 128B, XOR-swz

  // Q fragments (B-operand): lane holds Q[q=m31][d = dk*16 + hi*8 + j]
  bf16x8 qf[8];
  {
    const bf16* qp = Q + (size_t)(rowbase + qt*128 + wave*32 + m31) * D_MODEL
                   + h * HDIM + hi * 8;
#pragma unroll
    for (int dk = 0; dk < 8; dk++)
      qf[dk] = *(const bf16x8*)(qp + dk * 16);
  }

  f32x16 oacc[4];                     // C[m=d][n=q]: d = db*32 + crow(r,hi)
#pragma unroll
  for (int db = 0; db < 4; db++)
#pragma unroll
    for (int i = 0; i < 16; i++) oacc[db][i] = 0.f;
  float lsum = 0.f;

  // scale folded into exp2 domain: log2(e)/sqrt(128)
  const float SC2 = 0.12752051581562927f;

  const int ktmax = 2*qt + 1;
  const bf16* kbase0 = Kc + (size_t)rowbase * D_MODEL + h * HDIM;
  const bf16* vbase0 = VT + (size_t)(h*HDIM) * ldVT + rowbase;

  bf16x8 kr[4], vr[4];
#pragma unroll
  for (int c = 0; c < 4; c++) {          // prefetch tile 0
    int e = c*256 + t;
    kr[c] = *(const bf16x8*)(kbase0 + (size_t)(e >> 4) * D_MODEL + (e & 15) * 8);
    vr[c] = *(const bf16x8*)(vbase0 + (size_t)(e >> 3) * ldVT + (e & 7) * 8);
  }

  for (int kt = 0; kt <= ktmax; kt++) {
    // ---- commit prefetched tile to LDS (XOR-swizzled chunks) ----
#pragma unroll
    for (int c = 0; c < 4; c++) {
      int e = c*256 + t;
      int krow = e >> 4, kch = e & 15;
      *(bf16x8*)(Ks + krow * 128 + ((kch ^ (krow & 7)) * 8)) = kr[c];
      int vrow = e >> 3, vch = e & 7;
      *(bf16x8*)(Vs + vrow * 64  + ((vch ^ (vrow & 7)) * 8)) = vr[c];
    }
    __syncthreads();

    // ---- prefetch next tile into regs (overlaps compute below) ----
    if (kt < ktmax) {
      const bf16* kb = kbase0 + (size_t)((kt+1)*64) * D_MODEL;
      const bf16* vb = vbase0 + (kt+1)*64;
#pragma unroll
      for (int c = 0; c < 4; c++) {
        int e = c*256 + t;
        kr[c] = *(const bf16x8*)(kb + (size_t)(e >> 4) * D_MODEL + (e & 15) * 8);
        vr[c] = *(const bf16x8*)(vb + (size_t)(e >> 3) * ldVT + (e & 7) * 8);
      }
    }

    const int kvoff = kt*64 - qt*128;    // >=0 only for the 2 diagonal tiles
    // wave fully masked for this tile? (kvoff==64 and q_local <= 63)
    const bool activ = (kvoff < 0) | (kvoff <= wave*32 + 31);

    if (activ) {
      unsigned pb[4][4];                 // [kc 16-k chunk][B-frag dword]
#pragma unroll
      for (int kb = 0; kb < 2; kb++) {
        // ---- S^T = K Q^T (32k x 32q) ----
        f32x16 s;
#pragma unroll
        for (int i = 0; i < 16; i++) s[i] = 0.f;
        const int krow = kb*32 + m31;
        const bf16* ksrow = Ks + krow * 128;
        const int swz = (krow & 7);
#pragma unroll
        for (int dk = 0; dk < 8; dk++) {
          bf16x8 kf = *(const bf16x8*)(ksrow + (((dk*2 + hi) ^ swz) * 8));
          s = mfma32(kf, qf[dk], s);
        }

        // ---- static-max softmax numerator, lane-local ----
        float p[16];
        const int kq = kvoff + kb*32 + 4*hi - (wave*32 + m31);  // k - q offset
#pragma unroll
        for (int r = 0; r < 16; r++) {
          float v = s[r] * SC2;
          const int kk = (r & 3) + 8 * (r >> 2);
          if (kvoff >= 0 && (kq + kk) > 0) v = -1e30f;
          float e2 = exp2f(v);
          lsum += e2;
          p[r] = e2;
        }

        // ---- pack to PV B-operand: cvt_pk pairs + permlane32 half-swap ----
#pragma unroll
        for (int c = 0; c < 2; c++) {
          unsigned a0 = cvt_pk_bf16(p[(2*c)*4 + 0],   p[(2*c)*4 + 1]);
          unsigned a1 = cvt_pk_bf16(p[(2*c)*4 + 2],   p[(2*c)*4 + 3]);
          unsigned b0 = cvt_pk_bf16(p[(2*c+1)*4 + 0], p[(2*c+1)*4 + 1]);
          unsigned b1 = cvt_pk_bf16(p[(2*c+1)*4 + 2], p[(2*c+1)*4 + 3]);
          asm("v_permlane32_swap_b32 %0, %1" : "+v"(a0), "+v"(b0));
          asm("v_permlane32_swap_b32 %0, %1" : "+v"(a1), "+v"(b1));
          pb[kb*2 + c][0] = a0; pb[kb*2 + c][1] = a1;
          pb[kb*2 + c][2] = b0; pb[kb*2 + c][3] = b1;
        }
      }

      // ---- O^T += V^T P^T : C[m=d][n=q], A = V^T frags from LDS ----
#pragma unroll
      for (int db = 0; db < 4; db++) {
        const int vrow = db*32 + m31;
        const bf16* vsrow = Vs + vrow * 64;
        const int swz = (vrow & 7);
#pragma unroll
        for (int kc = 0; kc < 4; kc++) {
          bf16x8 vf = *(const bf16x8*)(vsrow + (((kc*2 + hi) ^ swz) * 8));
          u32x4 w = {pb[kc][0], pb[kc][1], pb[kc][2], pb[kc][3]};
          oacc[db] = mfma32(vf, __builtin_bit_cast(bf16x8, w), oacc[db]);
        }
      }
    }
    __syncthreads();
  }

  // ---- epilogue: combine half-row sums, scale, store (8B packed) ----
  const float ltot = lsum + __shfl_xor(lsum, 32, 64);
  const float invl = 1.f / ltot;
  const size_t ob = (size_t)(rowbase + qt*128 + wave*32 + m31) * D_MODEL + h * HDIM;
#pragma unroll
  for (int db = 0; db < 4; db++) {
#pragma unroll
    for (int q2 = 0; q2 < 4; q2++) {
      bf16x4 o4;
#pragma unroll
      for (int rr = 0; rr < 4; rr++)
        o4[rr] = (bf16)(oacc[db][q2*4 + rr] * invl);   // d = db*32+q2*8+hi*4+rr
      *(bf16x4*)(O + ob + db*32 + q2*8 + hi*4) = o4;
    }
  }
}

// ---------------------------------------------------------------------------
// Inputs FP32, output FP32. Path chosen by ws_size (deterministic, graph-safe).
//
// Full-path ws layout (35.65 MB == NEED_FULL, aliasing by liveness):
//   [0,16MB)  Kb   (K bf16)   <- holds wqb (8MB) until Q-GEMM, then split-K
//                                partials [0,32MB) until reduce_sk
//   [16,32MB) VTb  (V^T bf16) <- partials overlap; later wob (8MB) after attn
//   [32,34MB) Lt   (latent bf16)
// d_out scratch: [0,16MB) Q/ctx bf16; [16,32MB) xb (x in bf16, dead before
// the final fp32 output write).
// RoPE is fused into the Q-GEMM and gemm_kv(z=0) epilogues (no rope pass).
// ---------------------------------------------------------------------------
extern "C" void kernel_launch(void* const* d_in, const int* in_sizes, int n_in,
                              void* d_out, int out_size, void* d_ws, size_t ws_size,
                              hipStream_t stream)
{
  const float* x    = (const float*)d_in[0];
  const float* wq   = (const float*)d_in[1];
  const float* wdkv = (const float*)d_in[2];
  const float* wuk  = (const float*)d_in[3];
  const float* wuv  = (const float*)d_in[4];
  const float* wo   = (const float*)d_in[5];
  const float* bo   = (const float*)d_in[6];
  float* out = (float*)d_out;

  const size_t MTOT = (size_t)BATCH * BROWS;              // 4096
  const size_t NEED_FULL = (MTOT * D_MODEL + (size_t)D_MODEL * MTOT
                          + MTOT * LATENT) * sizeof(bf16);  // 35.7 MB

  if (ws_size >= NEED_FULL) {
    // ---------------- FULL-BATCH PATH ----------------
    bf16* Kb  = (bf16*)d_ws;                         // [4096][2048]
    bf16* VTb = Kb  + MTOT * D_MODEL;                // [2048][4096]
    bf16* Lt  = VTb + (size_t)D_MODEL * MTOT;        // [4096][256]
    bf16* wqb = Kb;                                  // aliases Kb (8 MB)
    bf16* wob = VTb;                                 // aliases VTb (8 MB)
    float* Pp = (float*)d_ws;                        // split-K partials, 32 MB
    bf16* sb  = (bf16*)out;                          // Q/ctx bf16, d_out[0,16M)
    bf16* xb  = sb + MTOT * D_MODEL;                 // x bf16,    d_out[16,32M)

    const int n8x = (int)(MTOT * D_MODEL / 8);                 // 1048576
    const int n8w = (int)((size_t)D_MODEL * D_MODEL / 8);      // 524288

    // 1) conversions: x (16MB bf16) and wq (8MB bf16), one fused launch
    cvt2_bf16<<<(n8x + n8w) / 256, 256, 0, stream>>>(x, xb, n8x, wq, wqb, n8w);

    // 2) Q = rope(xb @ wqb^T)  (8-wave GEMM, fused RoPE epilogue)
    gemm_bb<bf16, 0, 0, 1><<<dim3(32, 16), 512, 0, stream>>>(xb, wqb, sb, nullptr, (int)MTOT, D_MODEL, D_MODEL);

    // 3) latent: Lt = xb @ wdkv^T via split-K 8 (partials in dead Kb+VTb)
    gemm_bf_sk<8><<<dim3(32, 2, 8), 512, 0, stream>>>(xb, wdkv, Pp, (int)MTOT, LATENT, D_MODEL);
    reduce_sk<8><<<(int)(MTOT * LATENT / 4 / 256), 256, 0, stream>>>(Pp, Lt, (int)(MTOT * LATENT));
    //    xb, wqb, partials dead from here
    // 4) K (with fused RoPE) and V^T in ONE launch (1024 blocks = 4/CU)
    gemm_kv<<<dim3(32, 16, 2), 512, 0, stream>>>(Lt, wuk, wuv, Kb, VTb, (int)MTOT, D_MODEL, LATENT);

    flash_attn<<<dim3(512), 256, 0, stream>>>(sb, Kb, VTb, sb, (int)MTOT);

    // 5) wo -> bf16 into dead VTb region + ctx -> dead Kb region, one launch
    cvt_copy<<<(n8w + n8x) / 256 + 1, 256, 0, stream>>>(wo, wob, n8w, sb, Kb, n8x);

    // 6) out = ctx @ wob^T + bo  (8-wave GEMM, fp32 out)
    gemm_bb<float, 1, 0, 0><<<dim3(32, 16), 512, 0, stream>>>(Kb, wob, out, bo, (int)MTOT, D_MODEL, D_MODEL);
  } else {
    // ---------------- PER-BATCH PATH (16 MB ws) ----------------
    bf16* Kb  = (bf16*)d_ws;                         // [2048][2048] 8 MB
    bf16* VTb = Kb + (size_t)BROWS * D_MODEL;        // [2048][2048] 8 MB

    for (int b = 0; b < BATCH; b++) {
      const float* xb   = x   + (size_t)b * BROWS * D_MODEL;
      float*       outb = out + (size_t)b * BROWS * D_MODEL;
      bf16*        sb   = (bf16*)outb;               // Lt, then Q/ctx

      gemm_nt<float, float, bf16, 0, 0><<<dim3(16, 2),  256, 0, stream>>>(xb, wdkv, sb,  nullptr, BROWS, LATENT,  D_MODEL);
      gemm_nt<bf16,  float, bf16, 0, 0><<<dim3(16, 16), 256, 0, stream>>>(sb, wuk,  Kb,  nullptr, BROWS, D_MODEL, LATENT);
      gemm_nt<bf16,  float, bf16, 0, 1><<<dim3(16, 16), 256, 0, stream>>>(sb, wuv,  VTb, nullptr, BROWS, D_MODEL, LATENT);
      gemm_nt<float, float, bf16, 0, 0><<<dim3(16, 16), 256, 0, stream>>>(xb, wq,   sb,  nullptr, BROWS, D_MODEL, D_MODEL);

      rope_kernel<<<(BROWS * NHEAD * 8) / 256, 256, 0, stream>>>(sb, Kb);

      flash_attn<<<dim3(256), 256, 0, stream>>>(sb, Kb, VTb, sb, BROWS);

      hipMemcpyAsync(Kb, sb, (size_t)BROWS * D_MODEL * sizeof(bf16),
                     hipMemcpyDeviceToDevice, stream);
      gemm_nt<bf16, float, float, 1, 0><<<dim3(16, 16), 256, 0, stream>>>(Kb, wo, outb, bo, BROWS, D_MODEL, D_MODEL);
    }
  }
}